// Round 1
// baseline (925.620 us; speedup 1.0000x reference)
//
#include <hip/hip_runtime.h>
#include <stdint.h>

typedef unsigned short u16;
typedef __attribute__((ext_vector_type(8))) short short8;
typedef __attribute__((ext_vector_type(4))) float f32x4;
typedef __attribute__((ext_vector_type(4))) u16 u16x4;

// Problem constants: B=2, S=2048, H=4096, NH=32, NKV=8, HD=128, N_REP=4
static constexpr float SCALE = 0.08838834764831845f; // 128^-0.5

__device__ __forceinline__ u16 f2bf(float f) {
    union { float f; unsigned u; } x; x.f = f;
    unsigned r = x.u + 0x7fffu + ((x.u >> 16) & 1u); // RNE
    return (u16)(r >> 16);
}
__device__ __forceinline__ float bf2f(u16 b) {
    union { unsigned u; float f; } x; x.u = ((unsigned)b) << 16;
    return x.f;
}

// ---------------- f32 -> bf16 convert ----------------
__global__ __launch_bounds__(256) void convert_kernel(const float* __restrict__ src,
                                                      u16* __restrict__ dst, int n) {
    const int stride = gridDim.x * blockDim.x * 4;
    for (int i = (blockIdx.x * blockDim.x + threadIdx.x) * 4; i < n; i += stride) {
        float4 v = *reinterpret_cast<const float4*>(src + i);
        u16x4 o;
        o.x = f2bf(v.x); o.y = f2bf(v.y); o.z = f2bf(v.z); o.w = f2bf(v.w);
        *reinterpret_cast<u16x4*>(dst + i) = o;
    }
}

// ---------------- GEMM: C = A * B^T ----------------
// A: MxK bf16 row-major, B: NxK bf16 row-major (both K-contiguous).
// OUT_MODE 0: C bf16 row-major MxN; 1: C bf16 transposed (C[n*M+m]); 2: C f32 row-major.
// m97 structure: 128x128 tile, BK=64, 4 waves, global_load_lds(16B), 2 barriers/K-step.
// T2 swizzle via pre-swizzled global source column + swizzled ds_read (linear LDS dest).
template<int OUT_MODE>
__global__ __launch_bounds__(256) void gemm_bt(const u16* __restrict__ A,
                                               const u16* __restrict__ B,
                                               void* __restrict__ Cv,
                                               int M, int N, int K) {
    constexpr int BK = 64;
    __shared__ u16 sA[128 * BK];
    __shared__ u16 sB[128 * BK];
    const int tid = threadIdx.x;
    const int wid = tid >> 6, lane = tid & 63;
    const int lrow = lane & 15, lgrp = lane >> 4;
    const int row0 = blockIdx.x * 128, col0 = blockIdx.y * 128;
    const int wr = (wid >> 1) * 64, wc = (wid & 1) * 64;

    f32x4 acc[4][4] = {};

    const int NT = K / BK;
    for (int kt = 0; kt < NT; ++kt) {
        const int k0 = kt * BK;
        __syncthreads(); // prior compute done before overwrite
        #pragma unroll
        for (int rnd = 0; rnd < 4; ++rnd) {
            const int eoff = (rnd * 256 + tid) * 8;
            const int r = eoff >> 6, c = eoff & 63;
            const int gc = c ^ ((r & 7) << 3); // inverse (involution) swizzle on source
            const int ldsoff = rnd * 2048 + wid * 512; // wave-uniform; HW adds lane*16B
            __builtin_amdgcn_global_load_lds(
                (const __attribute__((address_space(1))) void*)(A + (size_t)(row0 + r) * K + k0 + gc),
                (__attribute__((address_space(3))) void*)(&sA[ldsoff]), 16, 0, 0);
            __builtin_amdgcn_global_load_lds(
                (const __attribute__((address_space(1))) void*)(B + (size_t)(col0 + r) * K + k0 + gc),
                (__attribute__((address_space(3))) void*)(&sB[ldsoff]), 16, 0, 0);
        }
        __syncthreads(); // staged data visible (vmcnt drained by barrier)
        #pragma unroll
        for (int kk = 0; kk < 2; ++kk) {
            const int koff = kk * 32 + lgrp * 8;
            short8 af[4], bfr[4];
            #pragma unroll
            for (int m = 0; m < 4; ++m) {
                const int rr = wr + m * 16 + lrow;
                af[m] = *(const short8*)&sA[rr * BK + (koff ^ ((rr & 7) << 3))];
            }
            #pragma unroll
            for (int n = 0; n < 4; ++n) {
                const int rr = wc + n * 16 + lrow;
                bfr[n] = *(const short8*)&sB[rr * BK + (koff ^ ((rr & 7) << 3))];
            }
            #pragma unroll
            for (int m = 0; m < 4; ++m)
                #pragma unroll
                for (int n = 0; n < 4; ++n)
                    acc[m][n] = __builtin_amdgcn_mfma_f32_16x16x32_bf16(af[m], bfr[n], acc[m][n], 0, 0, 0);
        }
    }

    // epilogue: C/D layout col=lane&15, row=(lane>>4)*4+reg
    const int orow = row0 + wr + lgrp * 4;
    const int ocol = col0 + wc + lrow;
    if (OUT_MODE == 2) {
        float* C = (float*)Cv;
        #pragma unroll
        for (int m = 0; m < 4; ++m)
            #pragma unroll
            for (int n = 0; n < 4; ++n)
                #pragma unroll
                for (int r = 0; r < 4; ++r)
                    C[(size_t)(orow + m * 16 + r) * N + ocol + n * 16] = acc[m][n][r];
    } else if (OUT_MODE == 0) {
        u16* C = (u16*)Cv;
        #pragma unroll
        for (int m = 0; m < 4; ++m)
            #pragma unroll
            for (int n = 0; n < 4; ++n)
                #pragma unroll
                for (int r = 0; r < 4; ++r)
                    C[(size_t)(orow + m * 16 + r) * N + ocol + n * 16] = f2bf(acc[m][n][r]);
    } else {
        u16* C = (u16*)Cv; // C[n*M + m], 4 consecutive m per lane -> 8B store
        #pragma unroll
        for (int m = 0; m < 4; ++m)
            #pragma unroll
            for (int n = 0; n < 4; ++n) {
                u16x4 pk;
                pk.x = f2bf(acc[m][n][0]); pk.y = f2bf(acc[m][n][1]);
                pk.z = f2bf(acc[m][n][2]); pk.w = f2bf(acc[m][n][3]);
                *(u16x4*)&C[(size_t)(ocol + n * 16) * M + orow + m * 16] = pk;
            }
    }
}

// ---------------- RoPE (in-place on bf16 Q or K) ----------------
template<int NHEADS>
__global__ __launch_bounds__(256) void rope_kernel(u16* __restrict__ X,
                                                   const float* __restrict__ cosb,
                                                   const float* __restrict__ sinb) {
    constexpr int LH = (NHEADS == 32) ? 5 : 3;
    const int total = 2 * 2048 * NHEADS * 64;
    const int stride = gridDim.x * blockDim.x;
    for (int i = blockIdx.x * blockDim.x + threadIdx.x; i < total; i += stride) {
        const int d = i & 63;
        const int h = (i >> 6) & (NHEADS - 1);
        const int rs = i >> (6 + LH); // b*S + s
        const size_t base = (size_t)rs * (NHEADS * 128) + h * 128 + d;
        const float c = cosb[rs * 128 + d];  // cos[d] == cos[d+64]
        const float sn = sinb[rs * 128 + d];
        const float x1 = bf2f(X[base]);
        const float x2 = bf2f(X[base + 64]);
        X[base] = f2bf(x1 * c - x2 * sn);
        X[base + 64] = f2bf(x2 * c + x1 * sn);
    }
}

// ---------------- flash attention (causal, GQA 4:1) ----------------
// Q: (B*S)x4096 roped bf16; K: (B*S)x1024 roped bf16; Vt: 1024x(B*S) bf16 (=V^T);
// AO: (B*S)x4096 bf16. Block: 4 waves, 64 q-rows (16/wave), KV tile 64.
__global__ __launch_bounds__(256) void attn_kernel(const u16* __restrict__ Q,
                                                   const u16* __restrict__ K,
                                                   const u16* __restrict__ Vt,
                                                   u16* __restrict__ AO) {
    __shared__ u16 sK[64 * 128];   // [kv][hd], XOR-swizzled rows (256B)
    __shared__ u16 sV[128 * 64];   // [hd][kv], XOR-swizzled rows (128B)
    __shared__ u16 sP[4][16 * 64]; // per-wave P, swizzled rows (128B)
    const int tid = threadIdx.x;
    const int wid = tid >> 6, lane = tid & 63;
    const int lrow = lane & 15, lgrp = lane >> 4;
    const int q0 = blockIdx.x * 64;
    const int h = blockIdx.y;
    const int b = blockIdx.z;
    const int hkv = h >> 2;   // N_REP = 4
    const int rs0 = b * 2048;

    short8 qf[4];
    {
        const u16* qb = Q + (size_t)(rs0 + q0 + wid * 16 + lrow) * 4096 + h * 128 + lgrp * 8;
        #pragma unroll
        for (int kk = 0; kk < 4; ++kk) qf[kk] = *(const short8*)(qb + kk * 32);
    }

    f32x4 accO[8] = {};
    float m_r[4], l_r[4];
    #pragma unroll
    for (int r = 0; r < 4; ++r) { m_r[r] = -1e30f; l_r[r] = 0.f; }

    const int NT = blockIdx.x + 1; // causal: only kv tiles 0..qt
    for (int t = 0; t < NT; ++t) {
        const int kv0 = t * 64;
        __syncthreads(); // previous iteration's LDS reads done
        #pragma unroll
        for (int it = 0; it < 4; ++it) {
            const int idx = (it * 256 + tid) * 8;
            const int r = idx >> 7, c = idx & 127;
            short8 v = *(const short8*)(K + (size_t)(rs0 + kv0 + r) * 1024 + hkv * 128 + c);
            *(short8*)&sK[r * 128 + (c ^ ((r & 7) << 3))] = v;
        }
        #pragma unroll
        for (int it = 0; it < 4; ++it) {
            const int idx = (it * 256 + tid) * 8;
            const int r = idx >> 6, c = idx & 63;
            short8 v = *(const short8*)(Vt + (size_t)(hkv * 128 + r) * 4096 + rs0 + kv0 + c);
            *(short8*)&sV[r * 64 + (c ^ ((r & 7) << 3))] = v;
        }
        __syncthreads();

        // QK^T: S-tile 16x64 per wave
        f32x4 sacc[4] = {};
        #pragma unroll
        for (int kk = 0; kk < 4; ++kk) {
            const int koff = kk * 32 + lgrp * 8;
            #pragma unroll
            for (int f = 0; f < 4; ++f) {
                const int kr = f * 16 + lrow;
                short8 kf = *(const short8*)&sK[kr * 128 + (koff ^ ((kr & 7) << 3))];
                sacc[f] = __builtin_amdgcn_mfma_f32_16x16x32_bf16(qf[kk], kf, sacc[f], 0, 0, 0);
            }
        }

        // scale + causal mask
        float sv[4][4];
        const int qrow_base = q0 + wid * 16 + lgrp * 4;
        #pragma unroll
        for (int f = 0; f < 4; ++f) {
            const int kv_abs = kv0 + f * 16 + lrow;
            #pragma unroll
            for (int r = 0; r < 4; ++r) {
                const float x = sacc[f][r] * SCALE;
                sv[f][r] = (kv_abs <= qrow_base + r) ? x : -1e30f;
            }
        }
        // online softmax: rows live in 16-lane groups
        float scl[4];
        #pragma unroll
        for (int r = 0; r < 4; ++r) {
            float mx = fmaxf(fmaxf(sv[0][r], sv[1][r]), fmaxf(sv[2][r], sv[3][r]));
            #pragma unroll
            for (int d = 1; d < 16; d <<= 1) mx = fmaxf(mx, __shfl_xor(mx, d));
            const float mnew = fmaxf(m_r[r], mx);
            scl[r] = __expf(m_r[r] - mnew);
            m_r[r] = mnew;
        }
        #pragma unroll
        for (int r = 0; r < 4; ++r) {
            float s = 0.f;
            #pragma unroll
            for (int f = 0; f < 4; ++f) {
                const float p = __expf(sv[f][r] - m_r[r]);
                sv[f][r] = p;
                s += p;
            }
            #pragma unroll
            for (int d = 1; d < 16; d <<= 1) s += __shfl_xor(s, d);
            l_r[r] = l_r[r] * scl[r] + s;
        }
        // P -> per-wave LDS (bf16, swizzled)
        #pragma unroll
        for (int f = 0; f < 4; ++f)
            #pragma unroll
            for (int r = 0; r < 4; ++r) {
                const int prow = lgrp * 4 + r;
                const int pc = f * 16 + lrow;
                sP[wid][prow * 64 + (pc ^ ((prow & 7) << 3))] = f2bf(sv[f][r]);
            }
        // rescale O
        #pragma unroll
        for (int n = 0; n < 8; ++n)
            #pragma unroll
            for (int r = 0; r < 4; ++r) accO[n][r] *= scl[r];
        // PV: P(16x64) * V(64x128)
        #pragma unroll
        for (int kk = 0; kk < 2; ++kk) {
            const int koff = kk * 32 + lgrp * 8;
            short8 pf = *(const short8*)&sP[wid][lrow * 64 + (koff ^ ((lrow & 7) << 3))];
            #pragma unroll
            for (int n = 0; n < 8; ++n) {
                const int vr = n * 16 + lrow;
                short8 vf = *(const short8*)&sV[vr * 64 + (koff ^ ((vr & 7) << 3))];
                accO[n] = __builtin_amdgcn_mfma_f32_16x16x32_bf16(pf, vf, accO[n], 0, 0, 0);
            }
        }
    }

    float inv[4];
    #pragma unroll
    for (int r = 0; r < 4; ++r) inv[r] = 1.0f / l_r[r];
    #pragma unroll
    for (int n = 0; n < 8; ++n)
        #pragma unroll
        for (int r = 0; r < 4; ++r) {
            const int q = q0 + wid * 16 + lgrp * 4 + r;
            AO[(size_t)(rs0 + q) * 4096 + h * 128 + n * 16 + lrow] = f2bf(accO[n][r] * inv[r]);
        }
}

extern "C" void kernel_launch(void* const* d_in, const int* in_sizes, int n_in,
                              void* d_out, int out_size, void* d_ws, size_t ws_size,
                              hipStream_t stream) {
    const float* hs   = (const float*)d_in[0];
    const float* cosp = (const float*)d_in[1];
    const float* sinp = (const float*)d_in[2];
    // d_in[3] = attention_mask: exact causal -> implemented analytically
    const float* Wq = (const float*)d_in[4];
    const float* Wk = (const float*)d_in[5];
    const float* Wv = (const float*)d_in[6];
    const float* Wo = (const float*)d_in[7];

    // d_out (64 MiB) doubles as scratch for Xb and Qb: both dead before the
    // final O-projection GEMM overwrites d_out with f32 results.
    u16* Xb = (u16*)d_out;              // 32 MiB: hidden bf16 (4096 x 4096)
    u16* Qb = (u16*)d_out + 16777216;   // 32 MiB: Q bf16 (4096 x 4096)
    char* w = (char*)d_ws;              // needs 128 MiB total
    u16* Wqb = (u16*)w; w += 33554432;
    u16* Wkb = (u16*)w; w += 8388608;
    u16* Wvb = (u16*)w; w += 8388608;
    u16* Wob = (u16*)w; w += 33554432;
    u16* Kb  = (u16*)w; w += 8388608;   // K bf16 (4096 x 1024)
    u16* Vtb = (u16*)w; w += 8388608;   // V^T bf16 (1024 x 4096)
    u16* AOb = (u16*)w; w += 33554432;  // attn out bf16 (4096 x 4096)

    convert_kernel<<<2048, 256, 0, stream>>>(hs, Xb, 16777216);
    convert_kernel<<<2048, 256, 0, stream>>>(Wq, Wqb, 16777216);
    convert_kernel<<<1024, 256, 0, stream>>>(Wk, Wkb, 4194304);
    convert_kernel<<<1024, 256, 0, stream>>>(Wv, Wvb, 4194304);
    convert_kernel<<<2048, 256, 0, stream>>>(Wo, Wob, 16777216);

    gemm_bt<0><<<dim3(32, 32), 256, 0, stream>>>(Xb, Wqb, Qb, 4096, 4096, 4096);
    gemm_bt<0><<<dim3(32, 8),  256, 0, stream>>>(Xb, Wkb, Kb, 4096, 1024, 4096);
    gemm_bt<1><<<dim3(32, 8),  256, 0, stream>>>(Xb, Wvb, Vtb, 4096, 1024, 4096);

    rope_kernel<32><<<2048, 256, 0, stream>>>(Qb, cosp, sinp);
    rope_kernel<8><<<1024, 256, 0, stream>>>(Kb, cosp, sinp);

    attn_kernel<<<dim3(32, 32, 2), 256, 0, stream>>>(Qb, Kb, Vtb, AOb);

    gemm_bt<2><<<dim3(32, 32), 256, 0, stream>>>(AOb, Wob, (float*)d_out, 4096, 4096, 4096);
}

// Round 2
// 886.462 us; speedup vs baseline: 1.0442x; 1.0442x over previous
//
#include <hip/hip_runtime.h>
#include <stdint.h>

typedef unsigned short u16;
typedef __attribute__((ext_vector_type(8))) short short8;
typedef __attribute__((ext_vector_type(4))) float f32x4;
typedef __attribute__((ext_vector_type(4))) u16 u16x4;

// Problem constants: B=2, S=2048, H=4096, NH=32, NKV=8, HD=128, N_REP=4
static constexpr float SCALE = 0.08838834764831845f; // 128^-0.5

__device__ __forceinline__ u16 f2bf(float f) {
    union { float f; unsigned u; } x; x.f = f;
    unsigned r = x.u + 0x7fffu + ((x.u >> 16) & 1u); // RNE
    return (u16)(r >> 16);
}
__device__ __forceinline__ float bf2f(u16 b) {
    union { unsigned u; float f; } x; x.u = ((unsigned)b) << 16;
    return x.f;
}

// ---------------- f32 -> bf16 convert ----------------
__global__ __launch_bounds__(256) void convert_kernel(const float* __restrict__ src,
                                                      u16* __restrict__ dst, int n) {
    const int stride = gridDim.x * blockDim.x * 4;
    for (int i = (blockIdx.x * blockDim.x + threadIdx.x) * 4; i < n; i += stride) {
        float4 v = *reinterpret_cast<const float4*>(src + i);
        u16x4 o;
        o.x = f2bf(v.x); o.y = f2bf(v.y); o.z = f2bf(v.z); o.w = f2bf(v.w);
        *reinterpret_cast<u16x4*>(dst + i) = o;
    }
}

// ---------------- GEMM: C = A * B^T ----------------
// A: MxK bf16 row-major, B: NxK bf16 row-major (both K-contiguous).
// OUT_MODE 0: C bf16 row-major MxN; 1: C bf16 transposed (C[n*M+m]); 2: C f32 row-major.
// m97 structure: 128x128 tile, BK=64, 4 waves, global_load_lds(16B), 2 barriers/K-step.
template<int OUT_MODE>
__global__ __launch_bounds__(256) void gemm_bt(const u16* __restrict__ A,
                                               const u16* __restrict__ B,
                                               void* __restrict__ Cv,
                                               int M, int N, int K) {
    constexpr int BK = 64;
    __shared__ u16 sA[128 * BK];
    __shared__ u16 sB[128 * BK];
    const int tid = threadIdx.x;
    const int wid = tid >> 6, lane = tid & 63;
    const int lrow = lane & 15, lgrp = lane >> 4;
    const int row0 = blockIdx.x * 128, col0 = blockIdx.y * 128;
    const int wr = (wid >> 1) * 64, wc = (wid & 1) * 64;

    f32x4 acc[4][4] = {};

    const int NT = K / BK;
    for (int kt = 0; kt < NT; ++kt) {
        const int k0 = kt * BK;
        __syncthreads();
        #pragma unroll
        for (int rnd = 0; rnd < 4; ++rnd) {
            const int eoff = (rnd * 256 + tid) * 8;
            const int r = eoff >> 6, c = eoff & 63;
            const int gc = c ^ ((r & 7) << 3);
            const int ldsoff = rnd * 2048 + wid * 512;
            __builtin_amdgcn_global_load_lds(
                (const __attribute__((address_space(1))) void*)(A + (size_t)(row0 + r) * K + k0 + gc),
                (__attribute__((address_space(3))) void*)(&sA[ldsoff]), 16, 0, 0);
            __builtin_amdgcn_global_load_lds(
                (const __attribute__((address_space(1))) void*)(B + (size_t)(col0 + r) * K + k0 + gc),
                (__attribute__((address_space(3))) void*)(&sB[ldsoff]), 16, 0, 0);
        }
        __syncthreads();
        #pragma unroll
        for (int kk = 0; kk < 2; ++kk) {
            const int koff = kk * 32 + lgrp * 8;
            short8 af[4], bfr[4];
            #pragma unroll
            for (int m = 0; m < 4; ++m) {
                const int rr = wr + m * 16 + lrow;
                af[m] = *(const short8*)&sA[rr * BK + (koff ^ ((rr & 7) << 3))];
            }
            #pragma unroll
            for (int n = 0; n < 4; ++n) {
                const int rr = wc + n * 16 + lrow;
                bfr[n] = *(const short8*)&sB[rr * BK + (koff ^ ((rr & 7) << 3))];
            }
            #pragma unroll
            for (int m = 0; m < 4; ++m)
                #pragma unroll
                for (int n = 0; n < 4; ++n)
                    acc[m][n] = __builtin_amdgcn_mfma_f32_16x16x32_bf16(af[m], bfr[n], acc[m][n], 0, 0, 0);
        }
    }

    const int orow = row0 + wr + lgrp * 4;
    const int ocol = col0 + wc + lrow;
    if (OUT_MODE == 2) {
        float* C = (float*)Cv;
        #pragma unroll
        for (int m = 0; m < 4; ++m)
            #pragma unroll
            for (int n = 0; n < 4; ++n)
                #pragma unroll
                for (int r = 0; r < 4; ++r)
                    C[(size_t)(orow + m * 16 + r) * N + ocol + n * 16] = acc[m][n][r];
    } else if (OUT_MODE == 0) {
        u16* C = (u16*)Cv;
        #pragma unroll
        for (int m = 0; m < 4; ++m)
            #pragma unroll
            for (int n = 0; n < 4; ++n)
                #pragma unroll
                for (int r = 0; r < 4; ++r)
                    C[(size_t)(orow + m * 16 + r) * N + ocol + n * 16] = f2bf(acc[m][n][r]);
    } else {
        u16* C = (u16*)Cv; // C[n*M + m]
        #pragma unroll
        for (int m = 0; m < 4; ++m)
            #pragma unroll
            for (int n = 0; n < 4; ++n) {
                u16x4 pk;
                pk.x = f2bf(acc[m][n][0]); pk.y = f2bf(acc[m][n][1]);
                pk.z = f2bf(acc[m][n][2]); pk.w = f2bf(acc[m][n][3]);
                *(u16x4*)&C[(size_t)(ocol + n * 16) * M + orow + m * 16] = pk;
            }
    }
}

// ---------------- RoPE (in-place on bf16 Q or K), optional extra scale ----------------
template<int NHEADS>
__global__ __launch_bounds__(256) void rope_kernel(u16* __restrict__ X,
                                                   const float* __restrict__ cosb,
                                                   const float* __restrict__ sinb,
                                                   float scale) {
    constexpr int LH = (NHEADS == 32) ? 5 : 3;
    const int total = 2 * 2048 * NHEADS * 64;
    const int stride = gridDim.x * blockDim.x;
    for (int i = blockIdx.x * blockDim.x + threadIdx.x; i < total; i += stride) {
        const int d = i & 63;
        const int h = (i >> 6) & (NHEADS - 1);
        const int rs = i >> (6 + LH);
        const size_t base = (size_t)rs * (NHEADS * 128) + h * 128 + d;
        const float c = cosb[rs * 128 + d] * scale;
        const float sn = sinb[rs * 128 + d] * scale;
        const float x1 = bf2f(X[base]);
        const float x2 = bf2f(X[base + 64]);
        X[base] = f2bf(x1 * c - x2 * sn);
        X[base + 64] = f2bf(x2 * c + x1 * sn);
    }
}

// ---------------- flash attention (causal, GQA 4:1) ----------------
// Q: (B*S)x4096 roped+pre-scaled bf16; K: (B*S)x1024 roped bf16;
// Vt: 1024x(B*S) bf16 (=V^T); AO: (B*S)x4096 bf16.
// Block: 4 waves, QBLK=128 (32 rows/wave), KVBLK=64, double-buffered async K/V
// staging via global_load_lds with pre-swizzled source, 1 barrier per tile.
__global__ __launch_bounds__(256, 2) void attn_kernel(const u16* __restrict__ Q,
                                                      const u16* __restrict__ K,
                                                      const u16* __restrict__ Vt,
                                                      u16* __restrict__ AO) {
    __shared__ u16 sK[2][64 * 128];   // [kv][hd], rows XOR-swizzled (256B rows)
    __shared__ u16 sV[2][128 * 64];   // [hd][kv], rows XOR-swizzled (128B rows)
    __shared__ u16 sP[4][32 * 64];    // per-wave P, swizzled (128B rows)
    const int tid = threadIdx.x;
    const int wid = tid >> 6, lane = tid & 63;
    const int lrow = lane & 15, lgrp = lane >> 4;
    const int q0 = blockIdx.x * 128;
    const int h = blockIdx.y;
    const int b = blockIdx.z;
    const int hkv = h >> 2;   // N_REP = 4
    const int rs0 = b * 2048;

    // Q fragments: rows q0 + wid*32 + m*16 + lrow (Q pre-scaled by SCALE in RoPE)
    short8 qf[2][4];
    #pragma unroll
    for (int m = 0; m < 2; ++m) {
        const u16* qb = Q + (size_t)(rs0 + q0 + wid * 32 + m * 16 + lrow) * 4096 + h * 128 + lgrp * 8;
        #pragma unroll
        for (int kk = 0; kk < 4; ++kk) qf[m][kk] = *(const short8*)(qb + kk * 32);
    }

    f32x4 accO[2][8] = {};
    float m_r[2][4], l_r[2][4];
    #pragma unroll
    for (int m = 0; m < 2; ++m)
        #pragma unroll
        for (int r = 0; r < 4; ++r) { m_r[m][r] = -1e30f; l_r[m][r] = 0.f; }

    // async staging: wave-uniform LDS dest, per-lane pre-swizzled global source
    auto stage = [&](int bf, int t) {
        const int kv0 = t * 64;
        #pragma unroll
        for (int i = 0; i < 4; ++i) {
            const int qd = wid * 4 + i;
            { // K tile: 64 rows x 128 elems; 1KB per instr = 4 rows
                const int r = qd * 4 + (lane >> 4);
                const int csrc = ((lane & 15) * 8) ^ ((r & 7) << 3);
                __builtin_amdgcn_global_load_lds(
                    (const __attribute__((address_space(1))) void*)(K + (size_t)(rs0 + kv0 + r) * 1024 + hkv * 128 + csrc),
                    (__attribute__((address_space(3))) void*)(&sK[bf][qd * 512]), 16, 0, 0);
            }
            { // V^T tile: 128 rows x 64 elems; 1KB per instr = 8 rows
                const int r = qd * 8 + (lane >> 3);
                const int csrc = ((lane & 7) * 8) ^ ((r & 7) << 3);
                __builtin_amdgcn_global_load_lds(
                    (const __attribute__((address_space(1))) void*)(Vt + (size_t)(hkv * 128 + r) * 4096 + rs0 + kv0 + csrc),
                    (__attribute__((address_space(3))) void*)(&sV[bf][qd * 512]), 16, 0, 0);
            }
        }
    };

    const int NT = 2 * blockIdx.x + 2; // causal
    stage(0, 0);
    __syncthreads();
    int buf = 0;

    for (int t = 0; t < NT; ++t) {
        if (t + 1 < NT) stage(buf ^ 1, t + 1); // prefetch hides under compute
        const int kv0 = t * 64;

        // QK^T: 32x64 S-tile per wave
        f32x4 sacc[2][4] = {};
        #pragma unroll
        for (int kk = 0; kk < 4; ++kk) {
            const int koff = kk * 32 + lgrp * 8;
            #pragma unroll
            for (int f = 0; f < 4; ++f) {
                const int kr = f * 16 + lrow;
                short8 kf = *(const short8*)&sK[buf][kr * 128 + (koff ^ ((kr & 7) << 3))];
                #pragma unroll
                for (int m = 0; m < 2; ++m)
                    sacc[m][f] = __builtin_amdgcn_mfma_f32_16x16x32_bf16(qf[m][kk], kf, sacc[m][f], 0, 0, 0);
            }
        }

        // mask + online softmax + P-write + O-rescale (per m)
        #pragma unroll
        for (int m = 0; m < 2; ++m) {
            const int rowb = q0 + wid * 32 + m * 16 + lgrp * 4;
            float sv[4][4];
            #pragma unroll
            for (int f = 0; f < 4; ++f) {
                const int kv_abs = kv0 + f * 16 + lrow;
                #pragma unroll
                for (int r = 0; r < 4; ++r)
                    sv[f][r] = (kv_abs <= rowb + r) ? sacc[m][f][r] : -1e30f;
            }
            float scl[4];
            #pragma unroll
            for (int r = 0; r < 4; ++r) {
                float mx = fmaxf(fmaxf(sv[0][r], sv[1][r]), fmaxf(sv[2][r], sv[3][r]));
                #pragma unroll
                for (int d = 1; d < 16; d <<= 1) mx = fmaxf(mx, __shfl_xor(mx, d));
                const float mnew = fmaxf(m_r[m][r], mx);
                scl[r] = __expf(m_r[m][r] - mnew);
                m_r[m][r] = mnew;
            }
            #pragma unroll
            for (int r = 0; r < 4; ++r) {
                float s = 0.f;
                #pragma unroll
                for (int f = 0; f < 4; ++f) {
                    const float p = __expf(sv[f][r] - m_r[m][r]);
                    sv[f][r] = p;
                    s += p;
                }
                #pragma unroll
                for (int d = 1; d < 16; d <<= 1) s += __shfl_xor(s, d);
                l_r[m][r] = l_r[m][r] * scl[r] + s;
            }
            #pragma unroll
            for (int f = 0; f < 4; ++f)
                #pragma unroll
                for (int r = 0; r < 4; ++r) {
                    const int prow = m * 16 + lgrp * 4 + r;
                    const int pc = f * 16 + lrow;
                    sP[wid][prow * 64 + (pc ^ ((prow & 7) << 3))] = f2bf(sv[f][r]);
                }
            #pragma unroll
            for (int n = 0; n < 8; ++n)
                #pragma unroll
                for (int r = 0; r < 4; ++r) accO[m][n][r] *= scl[r];
        }

        // PV: P(32x64) * V(64x128); compiler inserts lgkmcnt for sP dep
        #pragma unroll
        for (int kk = 0; kk < 2; ++kk) {
            const int koff = kk * 32 + lgrp * 8;
            short8 pf[2];
            #pragma unroll
            for (int m = 0; m < 2; ++m) {
                const int pr = m * 16 + lrow;
                pf[m] = *(const short8*)&sP[wid][pr * 64 + (koff ^ ((pr & 7) << 3))];
            }
            #pragma unroll
            for (int n = 0; n < 8; ++n) {
                const int vr = n * 16 + lrow;
                short8 vf = *(const short8*)&sV[buf][vr * 64 + (koff ^ ((vr & 7) << 3))];
                #pragma unroll
                for (int m = 0; m < 2; ++m)
                    accO[m][n] = __builtin_amdgcn_mfma_f32_16x16x32_bf16(pf[m], vf, accO[m][n], 0, 0, 0);
            }
        }
        __syncthreads(); // drains vmcnt (prefetch) + lgkmcnt; tile t+1 ready
        buf ^= 1;
    }

    #pragma unroll
    for (int m = 0; m < 2; ++m) {
        float inv[4];
        #pragma unroll
        for (int r = 0; r < 4; ++r) inv[r] = 1.0f / l_r[m][r];
        #pragma unroll
        for (int n = 0; n < 8; ++n)
            #pragma unroll
            for (int r = 0; r < 4; ++r) {
                const int q = q0 + wid * 32 + m * 16 + lgrp * 4 + r;
                AO[(size_t)(rs0 + q) * 4096 + h * 128 + n * 16 + lrow] = f2bf(accO[m][n][r] * inv[r]);
            }
    }
}

extern "C" void kernel_launch(void* const* d_in, const int* in_sizes, int n_in,
                              void* d_out, int out_size, void* d_ws, size_t ws_size,
                              hipStream_t stream) {
    const float* hs   = (const float*)d_in[0];
    const float* cosp = (const float*)d_in[1];
    const float* sinp = (const float*)d_in[2];
    // d_in[3] = attention_mask: exact causal -> implemented analytically
    const float* Wq = (const float*)d_in[4];
    const float* Wk = (const float*)d_in[5];
    const float* Wv = (const float*)d_in[6];
    const float* Wo = (const float*)d_in[7];

    u16* Xb = (u16*)d_out;              // 32 MiB
    u16* Qb = (u16*)d_out + 16777216;   // 32 MiB
    char* w = (char*)d_ws;              // 128 MiB total
    u16* Wqb = (u16*)w; w += 33554432;
    u16* Wkb = (u16*)w; w += 8388608;
    u16* Wvb = (u16*)w; w += 8388608;
    u16* Wob = (u16*)w; w += 33554432;
    u16* Kb  = (u16*)w; w += 8388608;
    u16* Vtb = (u16*)w; w += 8388608;
    u16* AOb = (u16*)w; w += 33554432;

    convert_kernel<<<2048, 256, 0, stream>>>(hs, Xb, 16777216);
    convert_kernel<<<2048, 256, 0, stream>>>(Wq, Wqb, 16777216);
    convert_kernel<<<1024, 256, 0, stream>>>(Wk, Wkb, 4194304);
    convert_kernel<<<1024, 256, 0, stream>>>(Wv, Wvb, 4194304);
    convert_kernel<<<2048, 256, 0, stream>>>(Wo, Wob, 16777216);

    gemm_bt<0><<<dim3(32, 32), 256, 0, stream>>>(Xb, Wqb, Qb, 4096, 4096, 4096);
    gemm_bt<0><<<dim3(32, 8),  256, 0, stream>>>(Xb, Wkb, Kb, 4096, 1024, 4096);
    gemm_bt<1><<<dim3(32, 8),  256, 0, stream>>>(Xb, Wvb, Vtb, 4096, 1024, 4096);

    rope_kernel<32><<<2048, 256, 0, stream>>>(Qb, cosp, sinp, SCALE); // fold QK^T scale into Q
    rope_kernel<8><<<1024, 256, 0, stream>>>(Kb, cosp, sinp, 1.0f);

    attn_kernel<<<dim3(16, 32, 2), 256, 0, stream>>>(Qb, Kb, Vtb, AOb);

    gemm_bt<2><<<dim3(32, 32), 256, 0, stream>>>(AOb, Wob, (float*)d_out, 4096, 4096, 4096);
}

// Round 3
// 683.832 us; speedup vs baseline: 1.3536x; 1.2963x over previous
//
#include <hip/hip_runtime.h>
#include <stdint.h>

typedef unsigned short u16;
typedef __attribute__((ext_vector_type(8))) short short8;
typedef __attribute__((ext_vector_type(4))) float f32x4;
typedef __attribute__((ext_vector_type(16))) float f32x16;
typedef __attribute__((ext_vector_type(4))) u16 u16x4;

// Problem constants: B=2, S=2048, H=4096, NH=32, NKV=8, HD=128, N_REP=4
static constexpr float SCALE = 0.08838834764831845f;        // 128^-0.5
static constexpr float QSCALE = 0.12752459769642898f;       // SCALE * log2(e)

__device__ __forceinline__ u16 f2bf(float f) {
    union { float f; unsigned u; } x; x.f = f;
    unsigned r = x.u + 0x7fffu + ((x.u >> 16) & 1u); // RNE
    return (u16)(r >> 16);
}
__device__ __forceinline__ float bf2f(u16 b) {
    union { unsigned u; float f; } x; x.u = ((unsigned)b) << 16;
    return x.f;
}
__device__ __forceinline__ unsigned cvt_pk_bf16(float lo, float hi_) {
    unsigned r;
    asm("v_cvt_pk_bf16_f32 %0, %1, %2" : "=v"(r) : "v"(lo), "v"(hi_));
    return r;
}

// ---------------- f32 -> bf16 convert ----------------
__global__ __launch_bounds__(256) void convert_kernel(const float* __restrict__ src,
                                                      u16* __restrict__ dst, int n) {
    const int stride = gridDim.x * blockDim.x * 4;
    for (int i = (blockIdx.x * blockDim.x + threadIdx.x) * 4; i < n; i += stride) {
        float4 v = *reinterpret_cast<const float4*>(src + i);
        u16x4 o;
        o.x = f2bf(v.x); o.y = f2bf(v.y); o.z = f2bf(v.z); o.w = f2bf(v.w);
        *reinterpret_cast<u16x4*>(dst + i) = o;
    }
}

// ---------------- GEMM: C = A * B^T (m97 structure, unchanged) ----------------
template<int OUT_MODE>
__global__ __launch_bounds__(256) void gemm_bt(const u16* __restrict__ A,
                                               const u16* __restrict__ B,
                                               void* __restrict__ Cv,
                                               int M, int N, int K) {
    constexpr int BK = 64;
    __shared__ u16 sA[128 * BK];
    __shared__ u16 sB[128 * BK];
    const int tid = threadIdx.x;
    const int wid = tid >> 6, lane = tid & 63;
    const int lrow = lane & 15, lgrp = lane >> 4;
    const int row0 = blockIdx.x * 128, col0 = blockIdx.y * 128;
    const int wr = (wid >> 1) * 64, wc = (wid & 1) * 64;

    f32x4 acc[4][4] = {};

    const int NT = K / BK;
    for (int kt = 0; kt < NT; ++kt) {
        const int k0 = kt * BK;
        __syncthreads();
        #pragma unroll
        for (int rnd = 0; rnd < 4; ++rnd) {
            const int eoff = (rnd * 256 + tid) * 8;
            const int r = eoff >> 6, c = eoff & 63;
            const int gc = c ^ ((r & 7) << 3);
            const int ldsoff = rnd * 2048 + wid * 512;
            __builtin_amdgcn_global_load_lds(
                (const __attribute__((address_space(1))) void*)(A + (size_t)(row0 + r) * K + k0 + gc),
                (__attribute__((address_space(3))) void*)(&sA[ldsoff]), 16, 0, 0);
            __builtin_amdgcn_global_load_lds(
                (const __attribute__((address_space(1))) void*)(B + (size_t)(col0 + r) * K + k0 + gc),
                (__attribute__((address_space(3))) void*)(&sB[ldsoff]), 16, 0, 0);
        }
        __syncthreads();
        #pragma unroll
        for (int kk = 0; kk < 2; ++kk) {
            const int koff = kk * 32 + lgrp * 8;
            short8 af[4], bfr[4];
            #pragma unroll
            for (int m = 0; m < 4; ++m) {
                const int rr = wr + m * 16 + lrow;
                af[m] = *(const short8*)&sA[rr * BK + (koff ^ ((rr & 7) << 3))];
            }
            #pragma unroll
            for (int n = 0; n < 4; ++n) {
                const int rr = wc + n * 16 + lrow;
                bfr[n] = *(const short8*)&sB[rr * BK + (koff ^ ((rr & 7) << 3))];
            }
            #pragma unroll
            for (int m = 0; m < 4; ++m)
                #pragma unroll
                for (int n = 0; n < 4; ++n)
                    acc[m][n] = __builtin_amdgcn_mfma_f32_16x16x32_bf16(af[m], bfr[n], acc[m][n], 0, 0, 0);
        }
    }

    const int orow = row0 + wr + lgrp * 4;
    const int ocol = col0 + wc + lrow;
    if (OUT_MODE == 2) {
        float* C = (float*)Cv;
        #pragma unroll
        for (int m = 0; m < 4; ++m)
            #pragma unroll
            for (int n = 0; n < 4; ++n)
                #pragma unroll
                for (int r = 0; r < 4; ++r)
                    C[(size_t)(orow + m * 16 + r) * N + ocol + n * 16] = acc[m][n][r];
    } else if (OUT_MODE == 0) {
        u16* C = (u16*)Cv;
        #pragma unroll
        for (int m = 0; m < 4; ++m)
            #pragma unroll
            for (int n = 0; n < 4; ++n)
                #pragma unroll
                for (int r = 0; r < 4; ++r)
                    C[(size_t)(orow + m * 16 + r) * N + ocol + n * 16] = f2bf(acc[m][n][r]);
    } else {
        u16* C = (u16*)Cv; // C[n*M + m]
        #pragma unroll
        for (int m = 0; m < 4; ++m)
            #pragma unroll
            for (int n = 0; n < 4; ++n) {
                u16x4 pk;
                pk.x = f2bf(acc[m][n][0]); pk.y = f2bf(acc[m][n][1]);
                pk.z = f2bf(acc[m][n][2]); pk.w = f2bf(acc[m][n][3]);
                *(u16x4*)&C[(size_t)(ocol + n * 16) * M + orow + m * 16] = pk;
            }
    }
}

// ---------------- RoPE (in-place on bf16 Q or K), optional extra scale ----------------
template<int NHEADS>
__global__ __launch_bounds__(256) void rope_kernel(u16* __restrict__ X,
                                                   const float* __restrict__ cosb,
                                                   const float* __restrict__ sinb,
                                                   float scale) {
    constexpr int LH = (NHEADS == 32) ? 5 : 3;
    const int total = 2 * 2048 * NHEADS * 64;
    const int stride = gridDim.x * blockDim.x;
    for (int i = blockIdx.x * blockDim.x + threadIdx.x; i < total; i += stride) {
        const int d = i & 63;
        const int h = (i >> 6) & (NHEADS - 1);
        const int rs = i >> (6 + LH);
        const size_t base = (size_t)rs * (NHEADS * 128) + h * 128 + d;
        const float c = cosb[rs * 128 + d] * scale;
        const float sn = sinb[rs * 128 + d] * scale;
        const float x1 = bf2f(X[base]);
        const float x2 = bf2f(X[base + 64]);
        X[base] = f2bf(x1 * c - x2 * sn);
        X[base + 64] = f2bf(x2 * c + x1 * sn);
    }
}

// ---------------- flash attention, 8-wave 32x32 swapped-QK^T structure ----------------
// Q: (B*S)x4096 roped bf16 pre-scaled by SCALE*log2e; K: (B*S)x1024 roped bf16;
// Vt: 1024x(B*S) bf16 (V^T); AO: (B*S)x4096 bf16.
// Block: 8 waves x 32 q-rows (QBLK=256), KVBLK=64, double-buffered async staging.
// Swapped QK^T: S^T = mfma(K, Q) -> lane owns q-col (lane&31), 32 kv scores in regs.
// In-register softmax (exp2 domain) + cvt_pk/shuffle P->A-frag for PV (no LDS P).
__global__ __launch_bounds__(512, 2) void attn_kernel(const u16* __restrict__ Q,
                                                      const u16* __restrict__ K,
                                                      const u16* __restrict__ Vt,
                                                      u16* __restrict__ AO) {
    __shared__ u16 sK[2][64 * 128];  // [kv][d], elem-col ^ ((row&15)<<3)
    __shared__ u16 sV[2][128 * 64];  // [d][kv], elem-col ^ ((row&7)<<3)
    const int tid = threadIdx.x;
    const int wid = tid >> 6, lane = tid & 63;
    const int l31 = lane & 31, hi = lane >> 5;

    // balanced block decode: paired blocks (c, c+256) get complementary depth
    const int gg = blockIdx.x >> 6;                // 0..7
    const int bx = (gg < 4) ? gg : 11 - gg;        // causal q-tile index 0..7
    const int rem = blockIdx.x & 63;
    const int h = rem >> 1;
    const int b = rem & 1;
    const int hkv = h >> 2;
    const int rs0 = b * 2048;
    const int q0 = bx * 256;
    const int qw = q0 + wid * 32;                  // this wave's first q row
    const int q_lane = qw + l31;                   // this lane's q row (softmax owner)

    // Q fragments (B-operand): lane holds q-col = l31, k = 16f + 8*hi + [0..7]
    short8 qf[8];
    {
        const u16* qb = Q + (size_t)(rs0 + q_lane) * 4096 + h * 128 + hi * 8;
        #pragma unroll
        for (int f = 0; f < 8; ++f) qf[f] = *(const short8*)(qb + f * 16);
    }

    f32x16 accO[4] = {};   // O^... D[q][d]: lane holds d-col = l31 (+32*d4), q = crow(r,hi)
    float m_c = -1e30f, l_c = 0.f;

    auto stage = [&](int bf, int t) {
        const int kv0 = t * 64;
        #pragma unroll
        for (int rnd = 0; rnd < 2; ++rnd) {
            { // K tile 64x128
                const int e = rnd * 4096 + tid * 8;
                const int r = e >> 7, c = e & 127;
                const int cs = c ^ ((r & 15) << 3);
                __builtin_amdgcn_global_load_lds(
                    (const __attribute__((address_space(1))) void*)(K + (size_t)(rs0 + kv0 + r) * 1024 + hkv * 128 + cs),
                    (__attribute__((address_space(3))) void*)(&sK[bf][rnd * 4096 + wid * 512]), 16, 0, 0);
            }
            { // V^T tile 128x64
                const int e = rnd * 4096 + tid * 8;
                const int r = e >> 6, c = e & 63;
                const int cs = c ^ ((r & 7) << 3);
                __builtin_amdgcn_global_load_lds(
                    (const __attribute__((address_space(1))) void*)(Vt + (size_t)(hkv * 128 + r) * 4096 + rs0 + kv0 + cs),
                    (__attribute__((address_space(3))) void*)(&sV[bf][rnd * 4096 + wid * 512]), 16, 0, 0);
            }
        }
    };

    const int NT = 4 * (bx + 1);
    stage(0, 0);
    __syncthreads();
    int buf = 0;

    for (int t = 0; t < NT; ++t) {
        if (t + 1 < NT) stage(buf ^ 1, t + 1);
        const int kv0 = t * 64;

        if (kv0 <= qw + 31) {  // wave-uniform causal skip
            // ---- QK^T (swapped): sc[blk] = K[32blk..][*] . Q^T -> D[kv][q] ----
            f32x16 sc[2] = {};
            #pragma unroll
            for (int f = 0; f < 8; ++f) {
                const int col = f * 16 + hi * 8;
                const int r0 = l31, r1 = 32 + l31;
                short8 k0 = *(const short8*)&sK[buf][r0 * 128 + (col ^ ((r0 & 15) << 3))];
                short8 k1 = *(const short8*)&sK[buf][r1 * 128 + (col ^ ((r1 & 15) << 3))];
                sc[0] = __builtin_amdgcn_mfma_f32_32x32x16_bf16(k0, qf[f], sc[0], 0, 0, 0);
                sc[1] = __builtin_amdgcn_mfma_f32_32x32x16_bf16(k1, qf[f], sc[1], 0, 0, 0);
            }

            // ---- mask (only on diagonal tiles) ----
            if (kv0 + 63 > q_lane) {
                #pragma unroll
                for (int blk = 0; blk < 2; ++blk)
                    #pragma unroll
                    for (int r = 0; r < 16; ++r) {
                        const int kv_abs = kv0 + blk * 32 + ((r & 3) + 8 * (r >> 2) + 4 * hi);
                        if (kv_abs > q_lane) sc[blk][r] = -1e30f;
                    }
            }

            // ---- in-register online softmax (exp2 domain) ----
            float mx = sc[0][0];
            #pragma unroll
            for (int blk = 0; blk < 2; ++blk)
                #pragma unroll
                for (int r = 0; r < 16; ++r) mx = fmaxf(mx, sc[blk][r]);
            mx = fmaxf(mx, __shfl_xor(mx, 32));

            if (!__all(mx <= m_c + 8.0f)) {   // T13 defer-max
                const float sclf = __builtin_amdgcn_exp2f(m_c - mx);
                m_c = mx;
                l_c *= sclf;
                float sclq[16];
                #pragma unroll
                for (int r = 0; r < 16; ++r)
                    sclq[r] = __shfl(sclf, (r & 3) + 8 * (r >> 2) + 4 * hi);
                #pragma unroll
                for (int d4 = 0; d4 < 4; ++d4)
                    #pragma unroll
                    for (int r = 0; r < 16; ++r) accO[d4][r] *= sclq[r];
            }
            float ssum = 0.f;
            #pragma unroll
            for (int blk = 0; blk < 2; ++blk)
                #pragma unroll
                for (int r = 0; r < 16; ++r) {
                    const float p = __builtin_amdgcn_exp2f(sc[blk][r] - m_c);
                    sc[blk][r] = p;
                    ssum += p;
                }
            ssum += __shfl_xor(ssum, 32);
            l_c += ssum;

            // ---- PV: build A-frags from P (cvt_pk + cross-half shuffle), MFMA ----
            #pragma unroll
            for (int blk = 0; blk < 2; ++blk) {
                #pragma unroll
                for (int tt = 0; tt < 2; ++tt) {
                    const unsigned cv00 = cvt_pk_bf16(sc[blk][8 * tt + 0], sc[blk][8 * tt + 1]);
                    const unsigned cv01 = cvt_pk_bf16(sc[blk][8 * tt + 2], sc[blk][8 * tt + 3]);
                    const unsigned cv10 = cvt_pk_bf16(sc[blk][8 * tt + 4], sc[blk][8 * tt + 5]);
                    const unsigned cv11 = cvt_pk_bf16(sc[blk][8 * tt + 6], sc[blk][8 * tt + 7]);
                    const unsigned s00 = __shfl_xor(cv00, 32);
                    const unsigned s01 = __shfl_xor(cv01, 32);
                    const unsigned s10 = __shfl_xor(cv10, 32);
                    const unsigned s11 = __shfl_xor(cv11, 32);
                    union { unsigned w[4]; short8 v; } pa;
                    pa.w[0] = hi ? s10 : cv00;
                    pa.w[1] = hi ? s11 : cv01;
                    pa.w[2] = hi ? cv10 : s00;
                    pa.w[3] = hi ? cv11 : s01;
                    const int kvb = blk * 32 + tt * 16 + hi * 8;
                    #pragma unroll
                    for (int d4 = 0; d4 < 4; ++d4) {
                        const int vr = d4 * 32 + l31;
                        short8 vf = *(const short8*)&sV[buf][vr * 64 + (kvb ^ ((vr & 7) << 3))];
                        accO[d4] = __builtin_amdgcn_mfma_f32_32x32x16_bf16(pa.v, vf, accO[d4], 0, 0, 0);
                    }
                }
            }
        }
        __syncthreads(); // prefetch (vmcnt) + this tile's LDS reads drained
        buf ^= 1;
    }

    // ---- epilogue: O[q][d] / l ----
    const float invl = 1.0f / l_c;
    float invq[16];
    #pragma unroll
    for (int r = 0; r < 16; ++r)
        invq[r] = __shfl(invl, (r & 3) + 8 * (r >> 2) + 4 * hi);
    #pragma unroll
    for (int d4 = 0; d4 < 4; ++d4)
        #pragma unroll
        for (int r = 0; r < 16; ++r) {
            const int q = qw + (r & 3) + 8 * (r >> 2) + 4 * hi;
            AO[(size_t)(rs0 + q) * 4096 + h * 128 + d4 * 32 + l31] = f2bf(accO[d4][r] * invq[r]);
        }
}

extern "C" void kernel_launch(void* const* d_in, const int* in_sizes, int n_in,
                              void* d_out, int out_size, void* d_ws, size_t ws_size,
                              hipStream_t stream) {
    const float* hs   = (const float*)d_in[0];
    const float* cosp = (const float*)d_in[1];
    const float* sinp = (const float*)d_in[2];
    // d_in[3] = attention_mask: exact causal -> implemented analytically
    const float* Wq = (const float*)d_in[4];
    const float* Wk = (const float*)d_in[5];
    const float* Wv = (const float*)d_in[6];
    const float* Wo = (const float*)d_in[7];

    u16* Xb = (u16*)d_out;              // 32 MiB
    u16* Qb = (u16*)d_out + 16777216;   // 32 MiB
    char* w = (char*)d_ws;              // 128 MiB total
    u16* Wqb = (u16*)w; w += 33554432;
    u16* Wkb = (u16*)w; w += 8388608;
    u16* Wvb = (u16*)w; w += 8388608;
    u16* Wob = (u16*)w; w += 33554432;
    u16* Kb  = (u16*)w; w += 8388608;
    u16* Vtb = (u16*)w; w += 8388608;
    u16* AOb = (u16*)w; w += 33554432;

    convert_kernel<<<2048, 256, 0, stream>>>(hs, Xb, 16777216);
    convert_kernel<<<2048, 256, 0, stream>>>(Wq, Wqb, 16777216);
    convert_kernel<<<1024, 256, 0, stream>>>(Wk, Wkb, 4194304);
    convert_kernel<<<1024, 256, 0, stream>>>(Wv, Wvb, 4194304);
    convert_kernel<<<2048, 256, 0, stream>>>(Wo, Wob, 16777216);

    gemm_bt<0><<<dim3(32, 32), 256, 0, stream>>>(Xb, Wqb, Qb, 4096, 4096, 4096);
    gemm_bt<0><<<dim3(32, 8),  256, 0, stream>>>(Xb, Wkb, Kb, 4096, 1024, 4096);
    gemm_bt<1><<<dim3(32, 8),  256, 0, stream>>>(Xb, Wvb, Vtb, 4096, 1024, 4096);

    rope_kernel<32><<<2048, 256, 0, stream>>>(Qb, cosp, sinp, QSCALE); // SCALE*log2e for exp2-softmax
    rope_kernel<8><<<1024, 256, 0, stream>>>(Kb, cosp, sinp, 1.0f);

    attn_kernel<<<512, 512, 0, stream>>>(Qb, Kb, Vtb, AOb);

    gemm_bt<2><<<dim3(32, 32), 256, 0, stream>>>(AOb, Wob, (float*)d_out, 4096, 4096, 4096);
}

// Round 4
// 674.141 us; speedup vs baseline: 1.3730x; 1.0144x over previous
//
#include <hip/hip_runtime.h>
#include <stdint.h>

typedef unsigned short u16;
typedef __attribute__((ext_vector_type(8))) short short8;
typedef __attribute__((ext_vector_type(4))) float f32x4;
typedef __attribute__((ext_vector_type(16))) float f32x16;
typedef __attribute__((ext_vector_type(4))) u16 u16x4;

// Problem constants: B=2, S=2048, H=4096, NH=32, NKV=8, HD=128, N_REP=4
static constexpr float SCALE = 0.08838834764831845f;        // 128^-0.5
static constexpr float QSCALE = 0.12752459769642898f;       // SCALE * log2(e)

__device__ __forceinline__ u16 f2bf(float f) {
    union { float f; unsigned u; } x; x.f = f;
    unsigned r = x.u + 0x7fffu + ((x.u >> 16) & 1u); // RNE
    return (u16)(r >> 16);
}
__device__ __forceinline__ float bf2f(u16 b) {
    union { unsigned u; float f; } x; x.u = ((unsigned)b) << 16;
    return x.f;
}
__device__ __forceinline__ unsigned cvt_pk_bf16(float lo, float hi_) {
    unsigned r;
    asm("v_cvt_pk_bf16_f32 %0, %1, %2" : "=v"(r) : "v"(lo), "v"(hi_));
    return r;
}

// ---------------- fused f32 -> bf16 convert for all 5 tensors ----------------
__global__ __launch_bounds__(256) void convert5_kernel(const float* __restrict__ s0, const float* __restrict__ s1,
                                                       const float* __restrict__ s2, const float* __restrict__ s3,
                                                       const float* __restrict__ s4,
                                                       u16* __restrict__ d0, u16* __restrict__ d1,
                                                       u16* __restrict__ d2, u16* __restrict__ d3,
                                                       u16* __restrict__ d4) {
    // float4 unit boundaries: hs 4M | Wq 4M | Wk 1M | Wv 1M | Wo 4M
    const int V0 = 4194304, V1 = 8388608, V2 = 9437184, V3 = 10485760, V4 = 14680064;
    const int stride = gridDim.x * blockDim.x;
    for (int i = blockIdx.x * blockDim.x + threadIdx.x; i < V4; i += stride) {
        const float* sp; u16* dp; int off;
        if (i < V0)      { sp = s0; dp = d0; off = i; }
        else if (i < V1) { sp = s1; dp = d1; off = i - V0; }
        else if (i < V2) { sp = s2; dp = d2; off = i - V1; }
        else if (i < V3) { sp = s3; dp = d3; off = i - V2; }
        else             { sp = s4; dp = d4; off = i - V3; }
        float4 v = *reinterpret_cast<const float4*>(sp + (size_t)off * 4);
        u16x4 o;
        o.x = f2bf(v.x); o.y = f2bf(v.y); o.z = f2bf(v.z); o.w = f2bf(v.w);
        *reinterpret_cast<u16x4*>(dp + (size_t)off * 4) = o;
    }
}

// ---------------- GEMM 128^2 (m97 structure) for the small K/V projections ----------------
// OUT_MODE 0: C bf16 row-major MxN; 1: C bf16 transposed (C[n*M+m]).
template<int OUT_MODE>
__global__ __launch_bounds__(256) void gemm_bt(const u16* __restrict__ A,
                                               const u16* __restrict__ B,
                                               void* __restrict__ Cv,
                                               int M, int N, int K) {
    constexpr int BK = 64;
    __shared__ u16 sA[128 * BK];
    __shared__ u16 sB[128 * BK];
    const int tid = threadIdx.x;
    const int wid = tid >> 6, lane = tid & 63;
    const int lrow = lane & 15, lgrp = lane >> 4;
    const int row0 = blockIdx.x * 128, col0 = blockIdx.y * 128;
    const int wr = (wid >> 1) * 64, wc = (wid & 1) * 64;

    f32x4 acc[4][4] = {};

    const int NT = K / BK;
    for (int kt = 0; kt < NT; ++kt) {
        const int k0 = kt * BK;
        __syncthreads();
        #pragma unroll
        for (int rnd = 0; rnd < 4; ++rnd) {
            const int eoff = (rnd * 256 + tid) * 8;
            const int r = eoff >> 6, c = eoff & 63;
            const int gc = c ^ ((r & 7) << 3);
            const int ldsoff = rnd * 2048 + wid * 512;
            __builtin_amdgcn_global_load_lds(
                (const __attribute__((address_space(1))) void*)(A + (size_t)(row0 + r) * K + k0 + gc),
                (__attribute__((address_space(3))) void*)(&sA[ldsoff]), 16, 0, 0);
            __builtin_amdgcn_global_load_lds(
                (const __attribute__((address_space(1))) void*)(B + (size_t)(col0 + r) * K + k0 + gc),
                (__attribute__((address_space(3))) void*)(&sB[ldsoff]), 16, 0, 0);
        }
        __syncthreads();
        #pragma unroll
        for (int kk = 0; kk < 2; ++kk) {
            const int koff = kk * 32 + lgrp * 8;
            short8 af[4], bfr[4];
            #pragma unroll
            for (int m = 0; m < 4; ++m) {
                const int rr = wr + m * 16 + lrow;
                af[m] = *(const short8*)&sA[rr * BK + (koff ^ ((rr & 7) << 3))];
            }
            #pragma unroll
            for (int n = 0; n < 4; ++n) {
                const int rr = wc + n * 16 + lrow;
                bfr[n] = *(const short8*)&sB[rr * BK + (koff ^ ((rr & 7) << 3))];
            }
            #pragma unroll
            for (int m = 0; m < 4; ++m)
                #pragma unroll
                for (int n = 0; n < 4; ++n)
                    acc[m][n] = __builtin_amdgcn_mfma_f32_16x16x32_bf16(af[m], bfr[n], acc[m][n], 0, 0, 0);
        }
    }

    const int orow = row0 + wr + lgrp * 4;
    const int ocol = col0 + wc + lrow;
    if (OUT_MODE == 0) {
        u16* C = (u16*)Cv;
        #pragma unroll
        for (int m = 0; m < 4; ++m)
            #pragma unroll
            for (int n = 0; n < 4; ++n)
                #pragma unroll
                for (int r = 0; r < 4; ++r)
                    C[(size_t)(orow + m * 16 + r) * N + ocol + n * 16] = f2bf(acc[m][n][r]);
    } else {
        u16* C = (u16*)Cv; // C[n*M + m]
        #pragma unroll
        for (int m = 0; m < 4; ++m)
            #pragma unroll
            for (int n = 0; n < 4; ++n) {
                u16x4 pk;
                pk.x = f2bf(acc[m][n][0]); pk.y = f2bf(acc[m][n][1]);
                pk.z = f2bf(acc[m][n][2]); pk.w = f2bf(acc[m][n][3]);
                *(u16x4*)&C[(size_t)(ocol + n * 16) * M + orow + m * 16] = pk;
            }
    }
}

// ---------------- GEMM 256^2, 8 waves, BK=32, ring-4 LDS, counted vmcnt ----------------
// C = A * B^T. A: MxK, B: NxK bf16 row-major. OUT_MODE 0: bf16 C; 2: f32 C.
// Counted-vmcnt pipeline (T3/T4): stage tile t+3 during compute of tile t;
// at each raw s_barrier wait only vmcnt(8) (2 tiles in flight) - never drain to 0.
// Swizzle: physical 16B-block = lgrp ^ ((row>>1)&3) -> conflict-free wave64 reads,
// staging source pre-swizzled (16B-granular, rule-21 both-sides involution).
template<int OUT_MODE>
__global__ __launch_bounds__(512, 2) void gemm256(const u16* __restrict__ A,
                                                  const u16* __restrict__ B,
                                                  void* __restrict__ Cv,
                                                  int M, int N, int K) {
    __shared__ u16 sA[4][8192];   // 4 slots x 256 rows x 32 elems = 64 KiB
    __shared__ u16 sB[4][8192];   // 64 KiB
    const int tid = threadIdx.x;
    const int wid = tid >> 6, lane = tid & 63;
    const int lrow = lane & 15, lgrp = lane >> 4;

    // bijective XCD swizzle (grid is a multiple of 8 here: 16x16=256)
    const int nbn = N >> 8;
    const int total = (M >> 8) * nbn;
    int bid = blockIdx.x;
    if ((total & 7) == 0) {
        const int cpx = total >> 3;
        bid = (bid & 7) * cpx + (bid >> 3);
    }
    const int row0 = (bid / nbn) * 256, col0 = (bid % nbn) * 256;
    const int wm = wid >> 2, wn = wid & 3;     // 2 x 4 wave grid
    const int wr = wm * 128, wc = wn * 64;     // per-wave 128x64 output

    f32x4 acc[8][4] = {};

    const int rS = wid * 16 + (lane >> 2);     // staging row within 128-row half
    const int jS = lane & 3;                   // 16B block within 64B row

    auto stage = [&](int s, int kt) {
        const int k0 = kt * 32;
        #pragma unroll
        for (int rd = 0; rd < 2; ++rd) {
            const int r = rd * 128 + rS;
            const int cs = k0 + ((jS ^ ((r >> 1) & 3)) << 3);  // inverse swizzle on source
            const int ldsoff = rd * 4096 + wid * 512;          // wave-uniform; HW adds lane*16B
            __builtin_amdgcn_global_load_lds(
                (const __attribute__((address_space(1))) void*)(A + (size_t)(row0 + r) * K + cs),
                (__attribute__((address_space(3))) void*)(&sA[s][ldsoff]), 16, 0, 0);
            __builtin_amdgcn_global_load_lds(
                (const __attribute__((address_space(1))) void*)(B + (size_t)(col0 + r) * K + cs),
                (__attribute__((address_space(3))) void*)(&sB[s][ldsoff]), 16, 0, 0);
        }
    };

    const int NK = K >> 5;    // BK = 32
    stage(0, 0); stage(1, 1); stage(2, 2);
    asm volatile("s_waitcnt vmcnt(8)" ::: "memory");  // tile 0 landed (tiles 1,2 in flight)
    __builtin_amdgcn_s_barrier();
    __builtin_amdgcn_sched_barrier(0);

    for (int t = 0; t < NK; ++t) {
        if (t + 3 < NK) stage((t + 3) & 3, t + 3);   // slot freed by the barrier ending t-1

        const u16* __restrict__ pA = sA[t & 3];
        const u16* __restrict__ pB = sB[t & 3];
        short8 a[8], bfr[4];
        #pragma unroll
        for (int m = 0; m < 8; ++m) {
            const int ra = wr + m * 16 + lrow;
            a[m] = *(const short8*)&pA[ra * 32 + ((lgrp ^ ((ra >> 1) & 3)) << 3)];
        }
        #pragma unroll
        for (int n = 0; n < 4; ++n) {
            const int rb = wc + n * 16 + lrow;
            bfr[n] = *(const short8*)&pB[rb * 32 + ((lgrp ^ ((rb >> 1) & 3)) << 3)];
        }
        __builtin_amdgcn_s_setprio(1);
        #pragma unroll
        for (int n = 0; n < 4; ++n)
            #pragma unroll
            for (int m = 0; m < 8; ++m)
                acc[m][n] = __builtin_amdgcn_mfma_f32_16x16x32_bf16(a[m], bfr[n], acc[m][n], 0, 0, 0);
        __builtin_amdgcn_s_setprio(0);

        if (t + 1 < NK) {
            // next tile must be landed for all waves after the barrier; keep rest in flight
            if (t + 3 < NK)        asm volatile("s_waitcnt vmcnt(8)" ::: "memory");
            else if (t + 3 == NK)  asm volatile("s_waitcnt vmcnt(4)" ::: "memory");
            else                   asm volatile("s_waitcnt vmcnt(0)" ::: "memory");
            __builtin_amdgcn_s_barrier();
            __builtin_amdgcn_sched_barrier(0);
        }
    }

    const int orow = row0 + wr + lgrp * 4;
    const int ocol = col0 + wc + lrow;
    if (OUT_MODE == 2) {
        float* C = (float*)Cv;
        #pragma unroll
        for (int m = 0; m < 8; ++m)
            #pragma unroll
            for (int n = 0; n < 4; ++n)
                #pragma unroll
                for (int r = 0; r < 4; ++r)
                    C[(size_t)(orow + m * 16 + r) * N + ocol + n * 16] = acc[m][n][r];
    } else {
        u16* C = (u16*)Cv;
        #pragma unroll
        for (int m = 0; m < 8; ++m)
            #pragma unroll
            for (int n = 0; n < 4; ++n)
                #pragma unroll
                for (int r = 0; r < 4; ++r)
                    C[(size_t)(orow + m * 16 + r) * N + ocol + n * 16] = f2bf(acc[m][n][r]);
    }
}

// ---------------- RoPE (in-place on bf16 Q or K), optional extra scale ----------------
template<int NHEADS>
__global__ __launch_bounds__(256) void rope_kernel(u16* __restrict__ X,
                                                   const float* __restrict__ cosb,
                                                   const float* __restrict__ sinb,
                                                   float scale) {
    constexpr int LH = (NHEADS == 32) ? 5 : 3;
    const int total = 2 * 2048 * NHEADS * 64;
    const int stride = gridDim.x * blockDim.x;
    for (int i = blockIdx.x * blockDim.x + threadIdx.x; i < total; i += stride) {
        const int d = i & 63;
        const int h = (i >> 6) & (NHEADS - 1);
        const int rs = i >> (6 + LH);
        const size_t base = (size_t)rs * (NHEADS * 128) + h * 128 + d;
        const float c = cosb[rs * 128 + d] * scale;
        const float sn = sinb[rs * 128 + d] * scale;
        const float x1 = bf2f(X[base]);
        const float x2 = bf2f(X[base + 64]);
        X[base] = f2bf(x1 * c - x2 * sn);
        X[base + 64] = f2bf(x2 * c + x1 * sn);
    }
}

// ---------------- flash attention, 8-wave 32x32 swapped-QK^T structure ----------------
__global__ __launch_bounds__(512, 2) void attn_kernel(const u16* __restrict__ Q,
                                                      const u16* __restrict__ K,
                                                      const u16* __restrict__ Vt,
                                                      u16* __restrict__ AO) {
    __shared__ u16 sK[2][64 * 128];  // [kv][d], elem-col ^ ((row&15)<<3)
    __shared__ u16 sV[2][128 * 64];  // [d][kv], elem-col ^ ((row&7)<<3)
    const int tid = threadIdx.x;
    const int wid = tid >> 6, lane = tid & 63;
    const int l31 = lane & 31, hi = lane >> 5;

    const int gg = blockIdx.x >> 6;                // 0..7
    const int bx = (gg < 4) ? gg : 11 - gg;        // causal q-tile index, load-balanced
    const int rem = blockIdx.x & 63;
    const int h = rem >> 1;
    const int b = rem & 1;
    const int hkv = h >> 2;
    const int rs0 = b * 2048;
    const int q0 = bx * 256;
    const int qw = q0 + wid * 32;
    const int q_lane = qw + l31;

    short8 qf[8];
    {
        const u16* qb = Q + (size_t)(rs0 + q_lane) * 4096 + h * 128 + hi * 8;
        #pragma unroll
        for (int f = 0; f < 8; ++f) qf[f] = *(const short8*)(qb + f * 16);
    }

    f32x16 accO[4] = {};
    float m_c = -1e30f, l_c = 0.f;

    auto stage = [&](int bf, int t) {
        const int kv0 = t * 64;
        #pragma unroll
        for (int rnd = 0; rnd < 2; ++rnd) {
            {
                const int e = rnd * 4096 + tid * 8;
                const int r = e >> 7, c = e & 127;
                const int cs = c ^ ((r & 15) << 3);
                __builtin_amdgcn_global_load_lds(
                    (const __attribute__((address_space(1))) void*)(K + (size_t)(rs0 + kv0 + r) * 1024 + hkv * 128 + cs),
                    (__attribute__((address_space(3))) void*)(&sK[bf][rnd * 4096 + wid * 512]), 16, 0, 0);
            }
            {
                const int e = rnd * 4096 + tid * 8;
                const int r = e >> 6, c = e & 63;
                const int cs = c ^ ((r & 7) << 3);
                __builtin_amdgcn_global_load_lds(
                    (const __attribute__((address_space(1))) void*)(Vt + (size_t)(hkv * 128 + r) * 4096 + rs0 + kv0 + cs),
                    (__attribute__((address_space(3))) void*)(&sV[bf][rnd * 4096 + wid * 512]), 16, 0, 0);
            }
        }
    };

    const int NT = 4 * (bx + 1);
    stage(0, 0);
    __syncthreads();
    int buf = 0;

    for (int t = 0; t < NT; ++t) {
        if (t + 1 < NT) stage(buf ^ 1, t + 1);
        const int kv0 = t * 64;

        if (kv0 <= qw + 31) {
            f32x16 sc[2] = {};
            #pragma unroll
            for (int f = 0; f < 8; ++f) {
                const int col = f * 16 + hi * 8;
                const int r0 = l31, r1 = 32 + l31;
                short8 k0 = *(const short8*)&sK[buf][r0 * 128 + (col ^ ((r0 & 15) << 3))];
                short8 k1 = *(const short8*)&sK[buf][r1 * 128 + (col ^ ((r1 & 15) << 3))];
                sc[0] = __builtin_amdgcn_mfma_f32_32x32x16_bf16(k0, qf[f], sc[0], 0, 0, 0);
                sc[1] = __builtin_amdgcn_mfma_f32_32x32x16_bf16(k1, qf[f], sc[1], 0, 0, 0);
            }

            if (kv0 + 63 > q_lane) {
                #pragma unroll
                for (int blk = 0; blk < 2; ++blk)
                    #pragma unroll
                    for (int r = 0; r < 16; ++r) {
                        const int kv_abs = kv0 + blk * 32 + ((r & 3) + 8 * (r >> 2) + 4 * hi);
                        if (kv_abs > q_lane) sc[blk][r] = -1e30f;
                    }
            }

            float mx = sc[0][0];
            #pragma unroll
            for (int blk = 0; blk < 2; ++blk)
                #pragma unroll
                for (int r = 0; r < 16; ++r) mx = fmaxf(mx, sc[blk][r]);
            mx = fmaxf(mx, __shfl_xor(mx, 32));

            if (!__all(mx <= m_c + 8.0f)) {
                const float sclf = __builtin_amdgcn_exp2f(m_c - mx);
                m_c = mx;
                l_c *= sclf;
                float sclq[16];
                #pragma unroll
                for (int r = 0; r < 16; ++r)
                    sclq[r] = __shfl(sclf, (r & 3) + 8 * (r >> 2) + 4 * hi);
                #pragma unroll
                for (int d4 = 0; d4 < 4; ++d4)
                    #pragma unroll
                    for (int r = 0; r < 16; ++r) accO[d4][r] *= sclq[r];
            }
            float ssum = 0.f;
            #pragma unroll
            for (int blk = 0; blk < 2; ++blk)
                #pragma unroll
                for (int r = 0; r < 16; ++r) {
                    const float p = __builtin_amdgcn_exp2f(sc[blk][r] - m_c);
                    sc[blk][r] = p;
                    ssum += p;
                }
            ssum += __shfl_xor(ssum, 32);
            l_c += ssum;

            #pragma unroll
            for (int blk = 0; blk < 2; ++blk) {
                #pragma unroll
                for (int tt = 0; tt < 2; ++tt) {
                    const unsigned cv00 = cvt_pk_bf16(sc[blk][8 * tt + 0], sc[blk][8 * tt + 1]);
                    const unsigned cv01 = cvt_pk_bf16(sc[blk][8 * tt + 2], sc[blk][8 * tt + 3]);
                    const unsigned cv10 = cvt_pk_bf16(sc[blk][8 * tt + 4], sc[blk][8 * tt + 5]);
                    const unsigned cv11 = cvt_pk_bf16(sc[blk][8 * tt + 6], sc[blk][8 * tt + 7]);
                    const unsigned s00 = __shfl_xor(cv00, 32);
                    const unsigned s01 = __shfl_xor(cv01, 32);
                    const unsigned s10 = __shfl_xor(cv10, 32);
                    const unsigned s11 = __shfl_xor(cv11, 32);
                    union { unsigned w[4]; short8 v; } pa;
                    pa.w[0] = hi ? s10 : cv00;
                    pa.w[1] = hi ? s11 : cv01;
                    pa.w[2] = hi ? cv10 : s00;
                    pa.w[3] = hi ? cv11 : s01;
                    const int kvb = blk * 32 + tt * 16 + hi * 8;
                    #pragma unroll
                    for (int d4 = 0; d4 < 4; ++d4) {
                        const int vr = d4 * 32 + l31;
                        short8 vf = *(const short8*)&sV[buf][vr * 64 + (kvb ^ ((vr & 7) << 3))];
                        accO[d4] = __builtin_amdgcn_mfma_f32_32x32x16_bf16(pa.v, vf, accO[d4], 0, 0, 0);
                    }
                }
            }
        }
        __syncthreads();
        buf ^= 1;
    }

    const float invl = 1.0f / l_c;
    float invq[16];
    #pragma unroll
    for (int r = 0; r < 16; ++r)
        invq[r] = __shfl(invl, (r & 3) + 8 * (r >> 2) + 4 * hi);
    #pragma unroll
    for (int d4 = 0; d4 < 4; ++d4)
        #pragma unroll
        for (int r = 0; r < 16; ++r) {
            const int q = qw + (r & 3) + 8 * (r >> 2) + 4 * hi;
            AO[(size_t)(rs0 + q) * 4096 + h * 128 + d4 * 32 + l31] = f2bf(accO[d4][r] * invq[r]);
        }
}

extern "C" void kernel_launch(void* const* d_in, const int* in_sizes, int n_in,
                              void* d_out, int out_size, void* d_ws, size_t ws_size,
                              hipStream_t stream) {
    const float* hs   = (const float*)d_in[0];
    const float* cosp = (const float*)d_in[1];
    const float* sinp = (const float*)d_in[2];
    // d_in[3] = attention_mask: exact causal -> implemented analytically
    const float* Wq = (const float*)d_in[4];
    const float* Wk = (const float*)d_in[5];
    const float* Wv = (const float*)d_in[6];
    const float* Wo = (const float*)d_in[7];

    u16* Xb = (u16*)d_out;              // 32 MiB (dead before O-proj overwrites)
    u16* Qb = (u16*)d_out + 16777216;   // 32 MiB
    char* w = (char*)d_ws;              // 128 MiB total
    u16* Wqb = (u16*)w; w += 33554432;
    u16* Wkb = (u16*)w; w += 8388608;
    u16* Wvb = (u16*)w; w += 8388608;
    u16* Wob = (u16*)w; w += 33554432;
    u16* Kb  = (u16*)w; w += 8388608;
    u16* Vtb = (u16*)w; w += 8388608;
    u16* AOb = (u16*)w; w += 33554432;

    convert5_kernel<<<4096, 256, 0, stream>>>(hs, Wq, Wk, Wv, Wo, Xb, Wqb, Wkb, Wvb, Wob);

    gemm256<0><<<256, 512, 0, stream>>>(Xb, Wqb, Qb, 4096, 4096, 4096);
    gemm_bt<0><<<dim3(32, 8), 256, 0, stream>>>(Xb, Wkb, Kb, 4096, 1024, 4096);
    gemm_bt<1><<<dim3(32, 8), 256, 0, stream>>>(Xb, Wvb, Vtb, 4096, 1024, 4096);

    rope_kernel<32><<<2048, 256, 0, stream>>>(Qb, cosp, sinp, QSCALE); // SCALE*log2e for exp2-softmax
    rope_kernel<8><<<1024, 256, 0, stream>>>(Kb, cosp, sinp, 1.0f);

    attn_kernel<<<512, 512, 0, stream>>>(Qb, Kb, Vtb, AOb);

    gemm256<2><<<256, 512, 0, stream>>>(AOb, Wob, (float*)d_out, 4096, 4096, 4096);
}

// Round 5
// 585.237 us; speedup vs baseline: 1.5816x; 1.1519x over previous
//
#include <hip/hip_runtime.h>
#include <stdint.h>

typedef unsigned short u16;
typedef __attribute__((ext_vector_type(8))) short short8;
typedef __attribute__((ext_vector_type(4))) float f32x4;
typedef __attribute__((ext_vector_type(16))) float f32x16;
typedef __attribute__((ext_vector_type(4))) u16 u16x4;

// Problem constants: B=2, S=2048, H=4096, NH=32, NKV=8, HD=128, N_REP=4
static constexpr float SCALE = 0.08838834764831845f;        // 128^-0.5
static constexpr float QSCALE = 0.12752459769642898f;       // SCALE * log2(e)

__device__ __forceinline__ u16 f2bf(float f) {
    union { float f; unsigned u; } x; x.f = f;
    unsigned r = x.u + 0x7fffu + ((x.u >> 16) & 1u); // RNE
    return (u16)(r >> 16);
}
__device__ __forceinline__ float bf2f(u16 b) {
    union { unsigned u; float f; } x; x.u = ((unsigned)b) << 16;
    return x.f;
}
__device__ __forceinline__ unsigned cvt_pk_bf16(float lo, float hi_) {
    unsigned r;
    asm("v_cvt_pk_bf16_f32 %0, %1, %2" : "=v"(r) : "v"(lo), "v"(hi_));
    return r;
}

// ---------------- fused f32 -> bf16 convert for all 5 tensors ----------------
__global__ __launch_bounds__(256) void convert5_kernel(const float* __restrict__ s0, const float* __restrict__ s1,
                                                       const float* __restrict__ s2, const float* __restrict__ s3,
                                                       const float* __restrict__ s4,
                                                       u16* __restrict__ d0, u16* __restrict__ d1,
                                                       u16* __restrict__ d2, u16* __restrict__ d3,
                                                       u16* __restrict__ d4) {
    // float4 unit boundaries: hs 4M | Wq 4M | Wk 1M | Wv 1M | Wo 4M
    const int V0 = 4194304, V1 = 8388608, V2 = 9437184, V3 = 10485760, V4 = 14680064;
    const int stride = gridDim.x * blockDim.x;
    for (int i = blockIdx.x * blockDim.x + threadIdx.x; i < V4; i += stride) {
        const float* sp; u16* dp; int off;
        if (i < V0)      { sp = s0; dp = d0; off = i; }
        else if (i < V1) { sp = s1; dp = d1; off = i - V0; }
        else if (i < V2) { sp = s2; dp = d2; off = i - V1; }
        else if (i < V3) { sp = s3; dp = d3; off = i - V2; }
        else             { sp = s4; dp = d4; off = i - V3; }
        float4 v = *reinterpret_cast<const float4*>(sp + (size_t)off * 4);
        u16x4 o;
        o.x = f2bf(v.x); o.y = f2bf(v.y); o.z = f2bf(v.z); o.w = f2bf(v.w);
        *reinterpret_cast<u16x4*>(dp + (size_t)off * 4) = o;
    }
}

// ---------------- GEMM 128^2 (m97 structure) for the small K/V projections ----------------
// OUT_MODE 0: C bf16 row-major MxN; 1: C bf16 transposed (C[n*M+m]).
template<int OUT_MODE>
__global__ __launch_bounds__(256) void gemm_bt(const u16* __restrict__ A,
                                               const u16* __restrict__ B,
                                               void* __restrict__ Cv,
                                               int M, int N, int K) {
    constexpr int BK = 64;
    __shared__ u16 sA[128 * BK];
    __shared__ u16 sB[128 * BK];
    const int tid = threadIdx.x;
    const int wid = tid >> 6, lane = tid & 63;
    const int lrow = lane & 15, lgrp = lane >> 4;
    const int row0 = blockIdx.x * 128, col0 = blockIdx.y * 128;
    const int wr = (wid >> 1) * 64, wc = (wid & 1) * 64;

    f32x4 acc[4][4] = {};

    const int NT = K / BK;
    for (int kt = 0; kt < NT; ++kt) {
        const int k0 = kt * BK;
        __syncthreads();
        #pragma unroll
        for (int rnd = 0; rnd < 4; ++rnd) {
            const int eoff = (rnd * 256 + tid) * 8;
            const int r = eoff >> 6, c = eoff & 63;
            const int gc = c ^ ((r & 7) << 3);
            const int ldsoff = rnd * 2048 + wid * 512;
            __builtin_amdgcn_global_load_lds(
                (const __attribute__((address_space(1))) void*)(A + (size_t)(row0 + r) * K + k0 + gc),
                (__attribute__((address_space(3))) void*)(&sA[ldsoff]), 16, 0, 0);
            __builtin_amdgcn_global_load_lds(
                (const __attribute__((address_space(1))) void*)(B + (size_t)(col0 + r) * K + k0 + gc),
                (__attribute__((address_space(3))) void*)(&sB[ldsoff]), 16, 0, 0);
        }
        __syncthreads();
        #pragma unroll
        for (int kk = 0; kk < 2; ++kk) {
            const int koff = kk * 32 + lgrp * 8;
            short8 af[4], bfr[4];
            #pragma unroll
            for (int m = 0; m < 4; ++m) {
                const int rr = wr + m * 16 + lrow;
                af[m] = *(const short8*)&sA[rr * BK + (koff ^ ((rr & 7) << 3))];
            }
            #pragma unroll
            for (int n = 0; n < 4; ++n) {
                const int rr = wc + n * 16 + lrow;
                bfr[n] = *(const short8*)&sB[rr * BK + (koff ^ ((rr & 7) << 3))];
            }
            #pragma unroll
            for (int m = 0; m < 4; ++m)
                #pragma unroll
                for (int n = 0; n < 4; ++n)
                    acc[m][n] = __builtin_amdgcn_mfma_f32_16x16x32_bf16(af[m], bfr[n], acc[m][n], 0, 0, 0);
        }
    }

    const int orow = row0 + wr + lgrp * 4;
    const int ocol = col0 + wc + lrow;
    if (OUT_MODE == 0) {
        u16* C = (u16*)Cv;
        #pragma unroll
        for (int m = 0; m < 4; ++m)
            #pragma unroll
            for (int n = 0; n < 4; ++n)
                #pragma unroll
                for (int r = 0; r < 4; ++r)
                    C[(size_t)(orow + m * 16 + r) * N + ocol + n * 16] = f2bf(acc[m][n][r]);
    } else {
        u16* C = (u16*)Cv; // C[n*M + m]
        #pragma unroll
        for (int m = 0; m < 4; ++m)
            #pragma unroll
            for (int n = 0; n < 4; ++n) {
                u16x4 pk;
                pk.x = f2bf(acc[m][n][0]); pk.y = f2bf(acc[m][n][1]);
                pk.z = f2bf(acc[m][n][2]); pk.w = f2bf(acc[m][n][3]);
                *(u16x4*)&C[(size_t)(ocol + n * 16) * M + orow + m * 16] = pk;
            }
    }
}

// ---------------- GEMM 256^2, 8 waves, BK=32, ring-4 LDS, counted vmcnt, 2-phase interleave ----------------
// C = A * B^T. A: MxK, B: NxK bf16 row-major. OUT_MODE 0: bf16 C; 2: f32 C.
// m201-style per-phase pattern at BK=32 granularity:
//   phase A: {read A0-3+B0-3 (8 ds_read_b128), stage A(t+3), bar, lgkmcnt(0), 16 MFMA, bar}
//   phase B: {read A4-7 (4 ds_read_b128),      stage B(t+3), bar, lgkmcnt(0), 16 MFMA, vmcnt(8), bar}
// vmcnt counted (8 = 2 K-tiles in flight), drained 8->4->0 only in the epilogue.
// Race-freedom: slot (t+3)&3 was last read in iteration t-1; stage issues >=1 barrier later.
template<int OUT_MODE>
__global__ __launch_bounds__(512, 2) void gemm256(const u16* __restrict__ A,
                                                  const u16* __restrict__ B,
                                                  void* __restrict__ Cv,
                                                  int M, int N, int K) {
    __shared__ u16 sA[4][8192];   // 4 slots x 256 rows x 32 elems = 64 KiB
    __shared__ u16 sB[4][8192];   // 64 KiB
    const int tid = threadIdx.x;
    const int wid = tid >> 6, lane = tid & 63;
    const int lrow = lane & 15, lgrp = lane >> 4;

    // bijective XCD swizzle (grid here is 256 = multiple of 8)
    const int nbn = N >> 8;
    const int total = (M >> 8) * nbn;
    int bid = blockIdx.x;
    if ((total & 7) == 0) {
        const int cpx = total >> 3;
        bid = (bid & 7) * cpx + (bid >> 3);
    }
    const int row0 = (bid / nbn) * 256, col0 = (bid % nbn) * 256;
    const int wm = wid >> 2, wn = wid & 3;     // 2 x 4 wave grid
    const int wr = wm * 128, wc = wn * 64;     // per-wave 128x64 output

    f32x4 acc[8][4] = {};

    const int rS = wid * 16 + (lane >> 2);     // staging row within 128-row half
    const int jS = lane & 3;                   // 16B block within 64B row

    auto stageA = [&](int kt) {
        const int s = kt & 3, k0 = kt * 32;
        #pragma unroll
        for (int rd = 0; rd < 2; ++rd) {
            const int r = rd * 128 + rS;
            const int cs = k0 + ((jS ^ ((r >> 1) & 3)) << 3);  // inverse swizzle on source
            __builtin_amdgcn_global_load_lds(
                (const __attribute__((address_space(1))) void*)(A + (size_t)(row0 + r) * K + cs),
                (__attribute__((address_space(3))) void*)(&sA[s][rd * 4096 + wid * 512]), 16, 0, 0);
        }
    };
    auto stageB = [&](int kt) {
        const int s = kt & 3, k0 = kt * 32;
        #pragma unroll
        for (int rd = 0; rd < 2; ++rd) {
            const int r = rd * 128 + rS;
            const int cs = k0 + ((jS ^ ((r >> 1) & 3)) << 3);
            __builtin_amdgcn_global_load_lds(
                (const __attribute__((address_space(1))) void*)(B + (size_t)(col0 + r) * K + cs),
                (__attribute__((address_space(3))) void*)(&sB[s][rd * 4096 + wid * 512]), 16, 0, 0);
        }
    };

    const int NK = K >> 5;    // BK = 32
    stageA(0); stageB(0); stageA(1); stageB(1); stageA(2); stageB(2);
    asm volatile("s_waitcnt vmcnt(8)" ::: "memory");  // tile 0 landed (tiles 1,2 in flight)
    __builtin_amdgcn_s_barrier();

    for (int t = 0; t < NK; ++t) {
        const u16* __restrict__ pA = sA[t & 3];
        const u16* __restrict__ pB = sB[t & 3];

        // ---- phase A: reads (A lower half + B), stage A(t+3) ----
        short8 a[4], b[4];
        #pragma unroll
        for (int m = 0; m < 4; ++m) {
            const int ra = wr + m * 16 + lrow;
            a[m] = *(const short8*)&pA[ra * 32 + ((lgrp ^ ((ra >> 1) & 3)) << 3)];
        }
        #pragma unroll
        for (int n = 0; n < 4; ++n) {
            const int rb = wc + n * 16 + lrow;
            b[n] = *(const short8*)&pB[rb * 32 + ((lgrp ^ ((rb >> 1) & 3)) << 3)];
        }
        if (t + 3 < NK) stageA(t + 3);
        __builtin_amdgcn_s_barrier();
        asm volatile("s_waitcnt lgkmcnt(0)" ::: "memory");
        __builtin_amdgcn_sched_barrier(0);
        __builtin_amdgcn_s_setprio(1);
        #pragma unroll
        for (int n = 0; n < 4; ++n)
            #pragma unroll
            for (int m = 0; m < 4; ++m)
                acc[m][n] = __builtin_amdgcn_mfma_f32_16x16x32_bf16(a[m], b[n], acc[m][n], 0, 0, 0);
        __builtin_amdgcn_s_setprio(0);
        __builtin_amdgcn_sched_barrier(0);
        __builtin_amdgcn_s_barrier();

        // ---- phase B: reads (A upper half), stage B(t+3) ----
        short8 a2[4];
        #pragma unroll
        for (int m = 0; m < 4; ++m) {
            const int ra = wr + 64 + m * 16 + lrow;
            a2[m] = *(const short8*)&pA[ra * 32 + ((lgrp ^ ((ra >> 1) & 3)) << 3)];
        }
        if (t + 3 < NK) stageB(t + 3);
        __builtin_amdgcn_s_barrier();
        asm volatile("s_waitcnt lgkmcnt(0)" ::: "memory");
        __builtin_amdgcn_sched_barrier(0);
        __builtin_amdgcn_s_setprio(1);
        #pragma unroll
        for (int n = 0; n < 4; ++n)
            #pragma unroll
            for (int m = 0; m < 4; ++m)
                acc[m + 4][n] = __builtin_amdgcn_mfma_f32_16x16x32_bf16(a2[m], b[n], acc[m + 4][n], 0, 0, 0);
        __builtin_amdgcn_s_setprio(0);
        __builtin_amdgcn_sched_barrier(0);
        // ---- end-of-K-tile: counted vmcnt (never drain in steady state) ----
        if (t < NK - 3)       { asm volatile("s_waitcnt vmcnt(8)" ::: "memory"); }
        else if (t == NK - 3) { asm volatile("s_waitcnt vmcnt(4)" ::: "memory"); }
        else if (t == NK - 2) { asm volatile("s_waitcnt vmcnt(0)" ::: "memory"); }
        __builtin_amdgcn_s_barrier();
    }

    const int orow = row0 + wr + lgrp * 4;
    const int ocol = col0 + wc + lrow;
    if (OUT_MODE == 2) {
        float* C = (float*)Cv;
        #pragma unroll
        for (int m = 0; m < 8; ++m)
            #pragma unroll
            for (int n = 0; n < 4; ++n)
                #pragma unroll
                for (int r = 0; r < 4; ++r)
                    C[(size_t)(orow + m * 16 + r) * N + ocol + n * 16] = acc[m][n][r];
    } else {
        u16* C = (u16*)Cv;
        #pragma unroll
        for (int m = 0; m < 8; ++m)
            #pragma unroll
            for (int n = 0; n < 4; ++n)
                #pragma unroll
                for (int r = 0; r < 4; ++r)
                    C[(size_t)(orow + m * 16 + r) * N + ocol + n * 16] = f2bf(acc[m][n][r]);
    }
}

// ---------------- RoPE (in-place on bf16 Q or K), optional extra scale ----------------
template<int NHEADS>
__global__ __launch_bounds__(256) void rope_kernel(u16* __restrict__ X,
                                                   const float* __restrict__ cosb,
                                                   const float* __restrict__ sinb,
                                                   float scale) {
    constexpr int LH = (NHEADS == 32) ? 5 : 3;
    const int total = 2 * 2048 * NHEADS * 64;
    const int stride = gridDim.x * blockDim.x;
    for (int i = blockIdx.x * blockDim.x + threadIdx.x; i < total; i += stride) {
        const int d = i & 63;
        const int h = (i >> 6) & (NHEADS - 1);
        const int rs = i >> (6 + LH);
        const size_t base = (size_t)rs * (NHEADS * 128) + h * 128 + d;
        const float c = cosb[rs * 128 + d] * scale;
        const float sn = sinb[rs * 128 + d] * scale;
        const float x1 = bf2f(X[base]);
        const float x2 = bf2f(X[base + 64]);
        X[base] = f2bf(x1 * c - x2 * sn);
        X[base + 64] = f2bf(x2 * c + x1 * sn);
    }
}

// ---------------- flash attention, 8-wave 32x32 swapped-QK^T structure ----------------
__global__ __launch_bounds__(512, 2) void attn_kernel(const u16* __restrict__ Q,
                                                      const u16* __restrict__ K,
                                                      const u16* __restrict__ Vt,
                                                      u16* __restrict__ AO) {
    __shared__ u16 sK[2][64 * 128];  // [kv][d], elem-col ^ ((row&15)<<3)
    __shared__ u16 sV[2][128 * 64];  // [d][kv], elem-col ^ ((row&7)<<3)
    const int tid = threadIdx.x;
    const int wid = tid >> 6, lane = tid & 63;
    const int l31 = lane & 31, hi = lane >> 5;

    const int gg = blockIdx.x >> 6;                // 0..7
    const int bx = (gg < 4) ? gg : 11 - gg;        // causal q-tile index, load-balanced
    const int rem = blockIdx.x & 63;
    const int h = rem >> 1;
    const int b = rem & 1;
    const int hkv = h >> 2;
    const int rs0 = b * 2048;
    const int q0 = bx * 256;
    const int qw = q0 + wid * 32;
    const int q_lane = qw + l31;

    short8 qf[8];
    {
        const u16* qb = Q + (size_t)(rs0 + q_lane) * 4096 + h * 128 + hi * 8;
        #pragma unroll
        for (int f = 0; f < 8; ++f) qf[f] = *(const short8*)(qb + f * 16);
    }

    f32x16 accO[4] = {};
    float m_c = -1e30f, l_c = 0.f;

    auto stage = [&](int bf, int t) {
        const int kv0 = t * 64;
        #pragma unroll
        for (int rnd = 0; rnd < 2; ++rnd) {
            {
                const int e = rnd * 4096 + tid * 8;
                const int r = e >> 7, c = e & 127;
                const int cs = c ^ ((r & 15) << 3);
                __builtin_amdgcn_global_load_lds(
                    (const __attribute__((address_space(1))) void*)(K + (size_t)(rs0 + kv0 + r) * 1024 + hkv * 128 + cs),
                    (__attribute__((address_space(3))) void*)(&sK[bf][rnd * 4096 + wid * 512]), 16, 0, 0);
            }
            {
                const int e = rnd * 4096 + tid * 8;
                const int r = e >> 6, c = e & 63;
                const int cs = c ^ ((r & 7) << 3);
                __builtin_amdgcn_global_load_lds(
                    (const __attribute__((address_space(1))) void*)(Vt + (size_t)(hkv * 128 + r) * 4096 + rs0 + kv0 + cs),
                    (__attribute__((address_space(3))) void*)(&sV[bf][rnd * 4096 + wid * 512]), 16, 0, 0);
            }
        }
    };

    const int NT = 4 * (bx + 1);
    stage(0, 0);
    __syncthreads();
    int buf = 0;

    for (int t = 0; t < NT; ++t) {
        if (t + 1 < NT) stage(buf ^ 1, t + 1);
        const int kv0 = t * 64;

        if (kv0 <= qw + 31) {
            f32x16 sc[2] = {};
            #pragma unroll
            for (int f = 0; f < 8; ++f) {
                const int col = f * 16 + hi * 8;
                const int r0 = l31, r1 = 32 + l31;
                short8 k0 = *(const short8*)&sK[buf][r0 * 128 + (col ^ ((r0 & 15) << 3))];
                short8 k1 = *(const short8*)&sK[buf][r1 * 128 + (col ^ ((r1 & 15) << 3))];
                sc[0] = __builtin_amdgcn_mfma_f32_32x32x16_bf16(k0, qf[f], sc[0], 0, 0, 0);
                sc[1] = __builtin_amdgcn_mfma_f32_32x32x16_bf16(k1, qf[f], sc[1], 0, 0, 0);
            }

            if (kv0 + 63 > q_lane) {
                #pragma unroll
                for (int blk = 0; blk < 2; ++blk)
                    #pragma unroll
                    for (int r = 0; r < 16; ++r) {
                        const int kv_abs = kv0 + blk * 32 + ((r & 3) + 8 * (r >> 2) + 4 * hi);
                        if (kv_abs > q_lane) sc[blk][r] = -1e30f;
                    }
            }

            float mx = sc[0][0];
            #pragma unroll
            for (int blk = 0; blk < 2; ++blk)
                #pragma unroll
                for (int r = 0; r < 16; ++r) mx = fmaxf(mx, sc[blk][r]);
            mx = fmaxf(mx, __shfl_xor(mx, 32));

            if (!__all(mx <= m_c + 8.0f)) {
                const float sclf = __builtin_amdgcn_exp2f(m_c - mx);
                m_c = mx;
                l_c *= sclf;
                float sclq[16];
                #pragma unroll
                for (int r = 0; r < 16; ++r)
                    sclq[r] = __shfl(sclf, (r & 3) + 8 * (r >> 2) + 4 * hi);
                #pragma unroll
                for (int d4 = 0; d4 < 4; ++d4)
                    #pragma unroll
                    for (int r = 0; r < 16; ++r) accO[d4][r] *= sclq[r];
            }
            float ssum = 0.f;
            #pragma unroll
            for (int blk = 0; blk < 2; ++blk)
                #pragma unroll
                for (int r = 0; r < 16; ++r) {
                    const float p = __builtin_amdgcn_exp2f(sc[blk][r] - m_c);
                    sc[blk][r] = p;
                    ssum += p;
                }
            ssum += __shfl_xor(ssum, 32);
            l_c += ssum;

            #pragma unroll
            for (int blk = 0; blk < 2; ++blk) {
                #pragma unroll
                for (int tt = 0; tt < 2; ++tt) {
                    const unsigned cv00 = cvt_pk_bf16(sc[blk][8 * tt + 0], sc[blk][8 * tt + 1]);
                    const unsigned cv01 = cvt_pk_bf16(sc[blk][8 * tt + 2], sc[blk][8 * tt + 3]);
                    const unsigned cv10 = cvt_pk_bf16(sc[blk][8 * tt + 4], sc[blk][8 * tt + 5]);
                    const unsigned cv11 = cvt_pk_bf16(sc[blk][8 * tt + 6], sc[blk][8 * tt + 7]);
                    const unsigned s00 = __shfl_xor(cv00, 32);
                    const unsigned s01 = __shfl_xor(cv01, 32);
                    const unsigned s10 = __shfl_xor(cv10, 32);
                    const unsigned s11 = __shfl_xor(cv11, 32);
                    union { unsigned w[4]; short8 v; } pa;
                    pa.w[0] = hi ? s10 : cv00;
                    pa.w[1] = hi ? s11 : cv01;
                    pa.w[2] = hi ? cv10 : s00;
                    pa.w[3] = hi ? cv11 : s01;
                    const int kvb = blk * 32 + tt * 16 + hi * 8;
                    #pragma unroll
                    for (int d4 = 0; d4 < 4; ++d4) {
                        const int vr = d4 * 32 + l31;
                        short8 vf = *(const short8*)&sV[buf][vr * 64 + (kvb ^ ((vr & 7) << 3))];
                        accO[d4] = __builtin_amdgcn_mfma_f32_32x32x16_bf16(pa.v, vf, accO[d4], 0, 0, 0);
                    }
                }
            }
        }
        __syncthreads();
        buf ^= 1;
    }

    const float invl = 1.0f / l_c;
    float invq[16];
    #pragma unroll
    for (int r = 0; r < 16; ++r)
        invq[r] = __shfl(invl, (r & 3) + 8 * (r >> 2) + 4 * hi);
    #pragma unroll
    for (int d4 = 0; d4 < 4; ++d4)
        #pragma unroll
        for (int r = 0; r < 16; ++r) {
            const int q = qw + (r & 3) + 8 * (r >> 2) + 4 * hi;
            AO[(size_t)(rs0 + q) * 4096 + h * 128 + d4 * 32 + l31] = f2bf(accO[d4][r] * invq[r]);
        }
}

extern "C" void kernel_launch(void* const* d_in, const int* in_sizes, int n_in,
                              void* d_out, int out_size, void* d_ws, size_t ws_size,
                              hipStream_t stream) {
    const float* hs   = (const float*)d_in[0];
    const float* cosp = (const float*)d_in[1];
    const float* sinp = (const float*)d_in[2];
    // d_in[3] = attention_mask: exact causal -> implemented analytically
    const float* Wq = (const float*)d_in[4];
    const float* Wk = (const float*)d_in[5];
    const float* Wv = (const float*)d_in[6];
    const float* Wo = (const float*)d_in[7];

    u16* Xb = (u16*)d_out;              // 32 MiB (dead before O-proj overwrites)
    u16* Qb = (u16*)d_out + 16777216;   // 32 MiB
    char* w = (char*)d_ws;              // 128 MiB total
    u16* Wqb = (u16*)w; w += 33554432;
    u16* Wkb = (u16*)w; w += 8388608;
    u16* Wvb = (u16*)w; w += 8388608;
    u16* Wob = (u16*)w; w += 33554432;
    u16* Kb  = (u16*)w; w += 8388608;
    u16* Vtb = (u16*)w; w += 8388608;
    u16* AOb = (u16*)w; w += 33554432;

    convert5_kernel<<<4096, 256, 0, stream>>>(hs, Wq, Wk, Wv, Wo, Xb, Wqb, Wkb, Wvb, Wob);

    gemm256<0><<<256, 512, 0, stream>>>(Xb, Wqb, Qb, 4096, 4096, 4096);
    gemm_bt<0><<<dim3(32, 8), 256, 0, stream>>>(Xb, Wkb, Kb, 4096, 1024, 4096);
    gemm_bt<1><<<dim3(32, 8), 256, 0, stream>>>(Xb, Wvb, Vtb, 4096, 1024, 4096);

    rope_kernel<32><<<2048, 256, 0, stream>>>(Qb, cosp, sinp, QSCALE); // SCALE*log2e for exp2-softmax
    rope_kernel<8><<<1024, 256, 0, stream>>>(Kb, cosp, sinp, 1.0f);

    attn_kernel<<<512, 512, 0, stream>>>(Qb, Kb, Vtb, AOb);

    gemm256<2><<<256, 512, 0, stream>>>(AOb, Wob, (float*)d_out, 4096, 4096, 4096);
}